// Round 2
// baseline (301.592 us; speedup 1.0000x reference)
//
#include <hip/hip_runtime.h>

typedef short bf16x8 __attribute__((ext_vector_type(8)));
typedef float f32x4 __attribute__((ext_vector_type(4)));

__device__ __forceinline__ unsigned short f2bf(float f) {
    unsigned u = __float_as_uint(f);
    unsigned r = (u + 0x7fffu + ((u >> 16) & 1u)) >> 16;
    return (unsigned short)r;
}
__device__ __forceinline__ float bf2f(unsigned short u) {
    return __uint_as_float(((unsigned)u) << 16);
}

// async 16B global->LDS (DMA path, no VGPR round-trip). LDS dest is
// wave-uniform base + lane*16 (HW rule) -- layout below is linear in lane order.
__device__ __forceinline__ void gload_lds16(const void* g, void* l) {
    __builtin_amdgcn_global_load_lds(
        (const __attribute__((address_space(1))) unsigned int*)g,
        (__attribute__((address_space(3))) unsigned int*)l, 16, 0, 0);
}

// ---------------- prep: W transposes, x cvt, csr=-1 init, degree hist ----
// deg is zeroed by a preceding hipMemsetAsync (stream-ordered).
__global__ void k_prep(const float* __restrict__ W1, unsigned short* __restrict__ W1T,
                       const float* __restrict__ W2, unsigned short* __restrict__ W2T,
                       const float* __restrict__ W3, unsigned short* __restrict__ W3T,
                       const float* __restrict__ x, unsigned short* __restrict__ xb,
                       int* __restrict__ csr, int Mcap,
                       const int* __restrict__ ei, int E, int* __restrict__ deg,
                       int DIN, int HC, int DOUT, int N)
{
    int i = blockIdx.x * blockDim.x + threadIdx.x;
    int n1 = DIN * HC;
    int n2 = n1 + HC * HC;
    int n3 = n2 + HC * DOUT;
    int n4 = n3 + N * DIN;
    int n5 = n4 + Mcap;
    int n6 = n5 + E;
    if (i < n1) {
        int k = i / HC, n = i - k * HC;
        W1T[n * DIN + k] = f2bf(W1[i]);
    } else if (i < n2) {
        int j = i - n1;
        int k = j / HC, n = j - k * HC;
        W2T[n * HC + k] = f2bf(W2[j]);
    } else if (i < n3) {
        int j = i - n2;
        int k = j / DOUT, n = j - k * DOUT;
        W3T[n * HC + k] = f2bf(W3[j]);
    } else if (i < n4) {
        int j = i - n3;
        xb[j] = f2bf(x[j]);
    } else if (i < n5) {
        csr[i - n4] = -1;           // pad sentinel
    } else if (i < n6) {
        atomicAdd(&deg[ei[E + (i - n5)]], 1);
    }
}

// scan of (deg+1) rounded up to multiple of 4 (padded segments)
__global__ void k_scan(const int* __restrict__ deg, int* __restrict__ off,
                       int* __restrict__ cur, int N) {
    __shared__ int sums[1024];
    int t = threadIdx.x;
    int chunk = (N + 1023) >> 10;
    int lo = t * chunk;
    int hi = lo + chunk; if (hi > N) hi = N;
    if (lo > N) lo = N;
    int s = 0;
    for (int i = lo; i < hi; ++i) s += (deg[i] + 4) & ~3;
    sums[t] = s;
    __syncthreads();
    for (int dd = 1; dd < 1024; dd <<= 1) {
        int v = (t >= dd) ? sums[t - dd] : 0;
        __syncthreads();
        sums[t] += v;
        __syncthreads();
    }
    int run = sums[t] - s;  // exclusive prefix
    for (int i = lo; i < hi; ++i) { off[i] = run; cur[i] = run; run += (deg[i] + 4) & ~3; }
    if (t == 1023) off[N] = run;
}
__global__ void k_fill(const int* __restrict__ ei, int E, int N,
                       int* cur, int* __restrict__ csr) {
    int i = blockIdx.x * blockDim.x + threadIdx.x;
    if (i < E) {
        int s = ei[i], d = ei[E + i];
        int pos = atomicAdd(&cur[d], 1);
        csr[pos] = s;
    } else if (i < E + N) {
        int nn = i - E;
        int pos = atomicAdd(&cur[nn], 1);
        csr[pos] = nn;
    }
}

// ---------------- GEMM (layer 3 / small-Nc path): register-only 64x64 ----
// DOAL: fused attention-logit epilogue (valid only when tiles_n==1, i.e. the
// wave's 64 cols are ALL output cols; layer 3, H=1). Per row:
// al_s[row] = sum_col acc*a_src -> 4 FMA + shfl_xor reduce over the 16 r-lanes.
template <bool OUTBF, bool DOAL>
__global__ __launch_bounds__(256) void k_gemm(
    const unsigned short* __restrict__ A, const unsigned short* __restrict__ BT,
    void* __restrict__ D, int M, int K, int Nc, int tiles_n,
    const float* __restrict__ asrc, const float* __restrict__ adst,
    float* __restrict__ als, float* __restrict__ ald)
{
    int wid = blockIdx.x * (blockDim.x >> 6) + (threadIdx.x >> 6);
    int tiles_m = (M + 63) >> 6;
    if (wid >= tiles_m * tiles_n) return;
    int lane = threadIdx.x & 63;
    int tm = wid / tiles_n, tn = wid - tm * tiles_n;
    int m0 = tm << 6, n0 = tn << 6;
    int r = lane & 15, q = lane >> 4;

    const unsigned short* Arow[4];
    const unsigned short* Brow[4];
#pragma unroll
    for (int i = 0; i < 4; ++i) {
        int row = m0 + 16 * i + r; row = row < M ? row : M - 1;
        Arow[i] = A + (size_t)row * K + q * 8;
        Brow[i] = BT + (size_t)(n0 + 16 * i + r) * K + q * 8;
    }

    f32x4 acc[4][4] = {};
    bf16x8 a[4], b[4], a2[4], b2[4];
#pragma unroll
    for (int i = 0; i < 4; ++i) {
        a[i] = *(const bf16x8*)(Arow[i]);
        b[i] = *(const bf16x8*)(Brow[i]);
    }
    for (int k0 = 0; k0 < K; k0 += 32) {
        int kn = k0 + 32;
        if (kn < K) {
#pragma unroll
            for (int i = 0; i < 4; ++i) {
                a2[i] = *(const bf16x8*)(Arow[i] + kn);
                b2[i] = *(const bf16x8*)(Brow[i] + kn);
            }
        }
#pragma unroll
        for (int i = 0; i < 4; ++i)
#pragma unroll
            for (int j = 0; j < 4; ++j)
                acc[i][j] = __builtin_amdgcn_mfma_f32_16x16x32_bf16(a[i], b[j], acc[i][j], 0, 0, 0);
        if (kn < K) {
#pragma unroll
            for (int i = 0; i < 4; ++i) { a[i] = a2[i]; b[i] = b2[i]; }
        }
    }
#pragma unroll
    for (int i = 0; i < 4; ++i) {
        int rowb = m0 + 16 * i + q * 4;
#pragma unroll
        for (int rr = 0; rr < 4; ++rr) {
            int row = rowb + rr;
            if (row < M) {
#pragma unroll
                for (int j = 0; j < 4; ++j) {
                    int col = n0 + 16 * j + r;
                    if (OUTBF)
                        ((unsigned short*)D)[(size_t)row * Nc + col] = f2bf(acc[i][j][rr]);
                    else
                        ((float*)D)[(size_t)row * Nc + col] = acc[i][j][rr];
                }
            }
        }
    }
    if (DOAL) {
        float asl[4], adl[4];
#pragma unroll
        for (int j = 0; j < 4; ++j) { asl[j] = asrc[16 * j + r]; adl[j] = adst[16 * j + r]; }
#pragma unroll
        for (int i = 0; i < 4; ++i) {
#pragma unroll
            for (int rr = 0; rr < 4; ++rr) {
                float s = 0.f, d = 0.f;
#pragma unroll
                for (int j = 0; j < 4; ++j) {
                    s += acc[i][j][rr] * asl[j];
                    d += acc[i][j][rr] * adl[j];
                }
#pragma unroll
                for (int dd = 1; dd < 16; dd <<= 1) {
                    s += __shfl_xor(s, dd);
                    d += __shfl_xor(d, dd);
                }
                int row = m0 + 16 * i + q * 4 + rr;
                if (r == 0 && row < M) { als[row] = s; ald[row] = d; }
            }
        }
    }
}

// ---------------- GEMM (layers 1&2): m97-style 128x64 tile, LDS-staged ----
// 4 waves (2x2), wave tile 64x32, BK=32. Staging via global_load_lds width 16:
// per K-step each wave DMAs 3 KiB (2 A chunks + 1 B chunk, 1 KiB each, linear
// lane order), 2 barriers per K-step (the measured-874TF m97 schedule).
// BN=64 keeps the grid at (M/128)*(Nc/64)=632 blocks (~2.5/CU) -- at M=10000
// grid occupancy, not per-wave ILP, is the binding constraint.
__global__ __launch_bounds__(256) void k_gemm_lds(
    const unsigned short* __restrict__ A, const unsigned short* __restrict__ BT,
    unsigned short* __restrict__ D, int M, int K, int Nc, int tiles_n)
{
    __shared__ unsigned short As[128 * 32];   // 8 KiB
    __shared__ unsigned short Bs[64 * 32];    // 4 KiB
    int tm = blockIdx.x / tiles_n, tn = blockIdx.x - tm * tiles_n;
    int m0 = tm << 7, n0 = tn << 6;
    int tid = threadIdx.x;
    int w = tid >> 6, lane = tid & 63;
    int wr = w >> 1, wc = w & 1;
    int r = lane & 15, q = lane >> 4;

    // staging: chunk c = 16 tile-rows; lane l -> row c*16 + l/4, bytes (l&3)*16
    int lrow = lane >> 2;
    int lch = (lane & 3) * 8;                  // in bf16 elements
    int ga0 = m0 + w * 16 + lrow;       if (ga0 >= M) ga0 = M - 1;
    int ga1 = m0 + (w + 4) * 16 + lrow; if (ga1 >= M) ga1 = M - 1;
    const unsigned short* pa0 = A + (size_t)ga0 * K + lch;
    const unsigned short* pa1 = A + (size_t)ga1 * K + lch;
    const unsigned short* pb  = BT + (size_t)(n0 + w * 16 + lrow) * K + lch;
    unsigned short* lA0 = As + w * 512;        // wave-uniform LDS chunk bases
    unsigned short* lA1 = As + (w + 4) * 512;
    unsigned short* lB  = Bs + w * 512;

    const unsigned short* arp = As + (wr * 64 + r) * 32 + q * 8;
    const unsigned short* brp = Bs + (wc * 32 + r) * 32 + q * 8;

    f32x4 acc[4][2] = {};
    for (int k0 = 0; k0 < K; k0 += 32) {
        gload_lds16(pa0 + k0, lA0);
        gload_lds16(pa1 + k0, lA1);
        gload_lds16(pb + k0, lB);
        __syncthreads();                        // compiler drains vmcnt(0) here
        bf16x8 a[4], b[2];
#pragma unroll
        for (int i = 0; i < 4; ++i) a[i] = *(const bf16x8*)(arp + i * 16 * 32);
#pragma unroll
        for (int j = 0; j < 2; ++j) b[j] = *(const bf16x8*)(brp + j * 16 * 32);
#pragma unroll
        for (int i = 0; i < 4; ++i)
#pragma unroll
            for (int j = 0; j < 2; ++j)
                acc[i][j] = __builtin_amdgcn_mfma_f32_16x16x32_bf16(a[i], b[j], acc[i][j], 0, 0, 0);
        __syncthreads();                        // protect LDS before next stage
    }
#pragma unroll
    for (int i = 0; i < 4; ++i) {
        int rowb = m0 + wr * 64 + 16 * i + q * 4;
#pragma unroll
        for (int rr = 0; rr < 4; ++rr) {
            int row = rowb + rr;
            if (row < M) {
#pragma unroll
                for (int j = 0; j < 2; ++j) {
                    int col = n0 + wc * 32 + 16 * j + r;
                    D[(size_t)row * Nc + col] = f2bf(acc[i][j][rr]);
                }
            }
        }
    }
}

// ---------------- attention logits per node: al_s, al_d (bf16 h) ----------
template <int HCt, int Ht>
__global__ __launch_bounds__(256) void k_al(
    const unsigned short* __restrict__ h, const float* __restrict__ asrc,
    const float* __restrict__ adst,
    float* __restrict__ als, float* __restrict__ ald, int N)
{
    int wid = blockIdx.x * (blockDim.x >> 6) + (threadIdx.x >> 6);
    if (wid >= N) return;
    int lane = threadIdx.x & 63;
    const int CH = HCt / 64;
    const int Gs = 64 / Ht;  // lanes per head
    float s = 0.f, d = 0.f;
    if constexpr (CH == 8) {
        const uint4* hr = (const uint4*)(h + (size_t)wid * HCt) + lane;
        uint4 hv = *hr;
        unsigned wds[4] = {hv.x, hv.y, hv.z, hv.w};
        const f32x4* as4 = (const f32x4*)(asrc + lane * 8);
        const f32x4* ad4 = (const f32x4*)(adst + lane * 8);
        f32x4 av0 = as4[0], av1 = as4[1], dv0 = ad4[0], dv1 = ad4[1];
        float hf[8];
#pragma unroll
        for (int wv = 0; wv < 4; ++wv) {
            hf[2 * wv]     = __uint_as_float(wds[wv] << 16);
            hf[2 * wv + 1] = __uint_as_float(wds[wv] & 0xffff0000u);
        }
#pragma unroll
        for (int j = 0; j < 4; ++j) {
            s += hf[j] * av0[j] + hf[4 + j] * av1[j];
            d += hf[j] * dv0[j] + hf[4 + j] * dv1[j];
        }
    } else {
        // CH == 1 (layer 3): one bf16 per lane
        float hv = bf2f(h[(size_t)wid * HCt + lane]);
        s = hv * asrc[lane];
        d = hv * adst[lane];
    }
#pragma unroll
    for (int dd = 1; dd < Gs; dd <<= 1) {
        s += __shfl_xor(s, dd);
        d += __shfl_xor(d, dd);
    }
    if ((lane & (Gs - 1)) == 0) {
        int hh = lane / Gs;
        als[wid * Ht + hh] = s;
        ald[wid * Ht + hh] = d;
    }
}

// ---------------- aggr HC=512 H=4, quad-edge, INLINE alpha ----------------
// Wave = (node, head); 4 edge-groups x 16 lanes; each group consumes FOUR
// edges/iter: one int4 csr + 4x uint4 h rows. alpha = exp(leaky(als[s]+ald[n]))
// computed inline (broadcast 4B als gather, L2-resident 160KB table) -- kills
// the k_alpha4 materialization round-trip + dstarr. Pads (csr<0) -> alpha=0.
// Segments padded to x4 -> no tail logic. Slab-sequential grid (head-major)
// keeps the h gather L2-resident per XCD.
// NOTE: no software pipeline — VGPR 16 / 8 waves per SIMD. Measured (r5,
// r8, r16): trading occupancy for per-wave ILP is net-negative here.
template <bool DOELU>
__global__ __launch_bounds__(256) void k_aggr4c(
    const unsigned short* __restrict__ h, const float* __restrict__ als,
    const float* __restrict__ ald,
    const int* __restrict__ off, const int* __restrict__ csr,
    const float* __restrict__ bias,
    unsigned short* __restrict__ outp, int N, int nodeBlocks)
{
    int head = blockIdx.x / nodeBlocks;
    int nb = blockIdx.x - head * nodeBlocks;
    int n = nb * 4 + (threadIdx.x >> 6);
    if (n >= N) return;
    int lane = threadIdx.x & 63;
    int g = lane >> 4;            // edge group 0..3
    int p = lane & 15;            // channel-lane within group
    int q0 = (off[n] >> 2) + g, q1 = off[n + 1] >> 2;
    float aldh = ald[n * 4 + head];   // wave-uniform

    float acc[8] = {};
    float den = 0.f;
    const unsigned short* hbase = h + head * 128 + p * 8;
    const int4* csr4 = (const int4*)csr;

    auto aof = [&](int ss) -> float {
        int sc = ss < 0 ? 0 : ss;
        float l = als[sc * 4 + head] + aldh;   // broadcast within group
        l = l > 0.f ? l : 0.2f * l;
        float e = __expf(l);
        return ss < 0 ? 0.f : e;
    };
    auto fmaq = [&](float a, const uint4& hq) {
        unsigned wds[4] = {hq.x, hq.y, hq.z, hq.w};
#pragma unroll
        for (int wv = 0; wv < 4; ++wv) {
            acc[2 * wv]     += a * __uint_as_float(wds[wv] << 16);
            acc[2 * wv + 1] += a * __uint_as_float(wds[wv] & 0xffff0000u);
        }
    };

    for (int q = q0; q < q1; q += 4) {
        int4 cs = csr4[q];
        int c0 = cs.x < 0 ? 0 : cs.x;   // pads: alpha=0, clamp address
        int c1 = cs.y < 0 ? 0 : cs.y;
        int c2 = cs.z < 0 ? 0 : cs.z;
        int c3 = cs.w < 0 ? 0 : cs.w;
        uint4 h0 = *(const uint4*)(hbase + ((size_t)(unsigned)c0 << 9));
        uint4 h1 = *(const uint4*)(hbase + ((size_t)(unsigned)c1 << 9));
        uint4 h2 = *(const uint4*)(hbase + ((size_t)(unsigned)c2 << 9));
        uint4 h3 = *(const uint4*)(hbase + ((size_t)(unsigned)c3 << 9));
        float a0 = aof(cs.x), a1 = aof(cs.y), a2 = aof(cs.z), a3 = aof(cs.w);
        den += (a0 + a1) + (a2 + a3);
        fmaq(a0, h0);
        fmaq(a1, h1);
        fmaq(a2, h2);
        fmaq(a3, h3);
    }

    den += __shfl_xor(den, 16);
    den += __shfl_xor(den, 32);
#pragma unroll
    for (int j = 0; j < 8; ++j) {
        acc[j] += __shfl_xor(acc[j], 16);
        acc[j] += __shfl_xor(acc[j], 32);
    }

    if (g == 0) {
        float inv = 1.f / den;
        int cb = head * 128 + p * 8;
        unsigned ww[4];
#pragma unroll
        for (int wv = 0; wv < 4; ++wv) {
            float v0 = acc[2 * wv] * inv + bias[cb + 2 * wv];
            float v1 = acc[2 * wv + 1] * inv + bias[cb + 2 * wv + 1];
            if (DOELU) {
                v0 = v0 > 0.f ? v0 : expm1f(v0);
                v1 = v1 > 0.f ? v1 : expm1f(v1);
            }
            ww[wv] = (unsigned)f2bf(v0) | ((unsigned)f2bf(v1) << 16);
        }
        uint4 o; o.x = ww[0]; o.y = ww[1]; o.z = ww[2]; o.w = ww[3];
        *((uint4*)(outp + (size_t)n * 512 + cb)) = o;
    }
}

// ---------------- layer-3 aggr (HC=64, H=1, bf16 h), quad-edge, inline exp
__global__ __launch_bounds__(256) void k_aggr1b(
    const unsigned short* __restrict__ h, const float* __restrict__ als,
    const float* __restrict__ aldv, const int* __restrict__ off,
    const int* __restrict__ csr, const float* __restrict__ bias,
    float* __restrict__ outp, int N)
{
    int n = blockIdx.x * (blockDim.x >> 6) + (threadIdx.x >> 6);
    if (n >= N) return;
    int lane = threadIdx.x & 63;
    int g = lane >> 4;
    int p = lane & 15;
    int q0 = (off[n] >> 2) + g, q1 = off[n + 1] >> 2;
    float aldh = aldv[n];

    float acc[4] = {};
    float den = 0.f;
    const unsigned short* hbase = h + p * 4;   // lane owns 4 bf16 (8B)
    const int4* csr4 = (const int4*)csr;

    auto aof = [&](int ss) -> float {
        int sc = ss < 0 ? 0 : ss;
        float l = als[sc] + aldh;
        l = l > 0.f ? l : 0.2f * l;
        float e = __expf(l);
        return ss < 0 ? 0.f : e;
    };
    auto fmaq = [&](float a, const uint2& hq) {
        den += a;
        acc[0] += a * __uint_as_float(hq.x << 16);
        acc[1] += a * __uint_as_float(hq.x & 0xffff0000u);
        acc[2] += a * __uint_as_float(hq.y << 16);
        acc[3] += a * __uint_as_float(hq.y & 0xffff0000u);
    };

    for (int q = q0; q < q1; q += 4) {
        int4 cs = csr4[q];
        float a0 = aof(cs.x), a1 = aof(cs.y), a2 = aof(cs.z), a3 = aof(cs.w);
        uint2 h0 = *(const uint2*)(hbase + ((size_t)(unsigned)(cs.x < 0 ? 0 : cs.x) << 6));
        uint2 h1 = *(const uint2*)(hbase + ((size_t)(unsigned)(cs.y < 0 ? 0 : cs.y) << 6));
        uint2 h2 = *(const uint2*)(hbase + ((size_t)(unsigned)(cs.z < 0 ? 0 : cs.z) << 6));
        uint2 h3 = *(const uint2*)(hbase + ((size_t)(unsigned)(cs.w < 0 ? 0 : cs.w) << 6));
        fmaq(a0, h0);
        fmaq(a1, h1);
        fmaq(a2, h2);
        fmaq(a3, h3);
    }

    den += __shfl_xor(den, 16);
    den += __shfl_xor(den, 32);
#pragma unroll
    for (int j = 0; j < 4; ++j) {
        acc[j] += __shfl_xor(acc[j], 16);
        acc[j] += __shfl_xor(acc[j], 32);
    }
    if (g == 0) {
        float inv = 1.f / den;
        f32x4 o;
#pragma unroll
        for (int j = 0; j < 4; ++j)
            o[j] = acc[j] * inv + bias[p * 4 + j];
        *((f32x4*)(outp + (size_t)n * 64 + p * 4)) = o;
    }
}

// --------------------------------------------------------------------------
extern "C" void kernel_launch(void* const* d_in, const int* in_sizes, int n_in,
                              void* d_out, int out_size, void* d_ws, size_t ws_size,
                              hipStream_t stream)
{
    const float* x   = (const float*)d_in[0];
    const int*   ei  = (const int*)d_in[1];
    const float* W1  = (const float*)d_in[2];
    const float* as1 = (const float*)d_in[3];
    const float* ad1 = (const float*)d_in[4];
    const float* b1  = (const float*)d_in[5];
    const float* W2  = (const float*)d_in[6];
    const float* as2 = (const float*)d_in[7];
    const float* ad2 = (const float*)d_in[8];
    const float* b2  = (const float*)d_in[9];
    const float* W3  = (const float*)d_in[10];
    const float* as3 = (const float*)d_in[11];
    const float* ad3 = (const float*)d_in[12];
    const float* b3  = (const float*)d_in[13];

    const int DIN = 256, HC = 512, DOUT = 64;
    int N = in_sizes[0] / DIN;
    int E = in_sizes[1] / 2;
    int Mcap = E + 4 * N;  // capacity for 4-padded CSR

    // workspace carve-up
    char* w = (char*)d_ws;
    auto alloc = [&](size_t bytes) -> char* {
        char* p = w;
        w += (bytes + 255) & ~(size_t)255;
        return p;
    };
    int* deg    = (int*)alloc((size_t)N * 4);
    int* cur    = (int*)alloc((size_t)N * 4);
    int* off    = (int*)alloc((size_t)(N + 1) * 4);
    int* csr    = (int*)alloc((size_t)Mcap * 4);
    unsigned short* W1T = (unsigned short*)alloc((size_t)HC * DIN * 2);
    unsigned short* W2T = (unsigned short*)alloc((size_t)HC * HC * 2);
    unsigned short* W3T = (unsigned short*)alloc((size_t)DOUT * HC * 2);
    unsigned short* xb  = (unsigned short*)alloc((size_t)N * DIN * 2);
    unsigned short* act = (unsigned short*)alloc((size_t)N * HC * 2);
    unsigned short* hb  = (unsigned short*)alloc((size_t)N * HC * 2);
    unsigned short* hb3 = (unsigned short*)alloc((size_t)N * DOUT * 2);  // bf16 h (layer 3)
    float* als   = (float*)alloc((size_t)N * 4 * 4);
    float* ald   = (float*)alloc((size_t)N * 4 * 4);

    // ---- build: memset(deg) -> prep(+csr init+hist) -> scan -> fill ----
    hipMemsetAsync(deg, 0, (size_t)N * 4, stream);
    int prep_total = DIN * HC + HC * HC + HC * DOUT + N * DIN + Mcap + E;
    k_prep<<<(prep_total + 255) / 256, 256, 0, stream>>>(
        W1, W1T, W2, W2T, W3, W3T, x, xb, csr, Mcap, ei, E, deg, DIN, HC, DOUT, N);
    k_scan<<<1, 1024, 0, stream>>>(deg, off, cur, N);
    k_fill<<<(E + N + 255) / 256, 256, 0, stream>>>(ei, E, N, cur, csr);

    int tiles_m = (N + 63) / 64;
    auto gemm_blocks = [&](int tn) { return (tiles_m * tn + 3) / 4; };
    int tm128 = (N + 127) / 128;
    int nwave_blocks = (N + 3) / 4;
    int nodeBlocks = (N + 3) / 4;

    // ---- layer 1 ----
    k_gemm_lds<<<tm128 * (HC / 64), 256, 0, stream>>>(xb, W1T, hb, N, DIN, HC, HC / 64);
    k_al<512, 4><<<nwave_blocks, 256, 0, stream>>>(hb, as1, ad1, als, ald, N);
    k_aggr4c<true><<<4 * nodeBlocks, 256, 0, stream>>>(hb, als, ald, off, csr, b1, act, N, nodeBlocks);

    // ---- layer 2 ----
    k_gemm_lds<<<tm128 * (HC / 64), 256, 0, stream>>>(act, W2T, hb, N, HC, HC, HC / 64);
    k_al<512, 4><<<nwave_blocks, 256, 0, stream>>>(hb, as2, ad2, als, ald, N);
    k_aggr4c<true><<<4 * nodeBlocks, 256, 0, stream>>>(hb, als, ald, off, csr, b2, act, N, nodeBlocks);

    // ---- layer 3 (bf16 h path; Nc=64, al fused into GEMM epilogue) ----
    k_gemm<true, true><<<gemm_blocks(1), 256, 0, stream>>>(
        act, W3T, hb3, N, HC, DOUT, 1, as3, ad3, als, ald);
    k_aggr1b<<<nwave_blocks, 256, 0, stream>>>(hb3, als, ald, off, csr, b3, (float*)d_out, N);
}

// Round 3
// 294.527 us; speedup vs baseline: 1.0240x; 1.0240x over previous
//
#include <hip/hip_runtime.h>
#include <hip/hip_fp16.h>

typedef _Float16 f16x8 __attribute__((ext_vector_type(8)));
typedef float f32x4 __attribute__((ext_vector_type(4)));

__device__ __forceinline__ unsigned short f2h_bits(float f) {
    __half h = __float2half(f);
    return *reinterpret_cast<unsigned short*>(&h);
}
__device__ __forceinline__ float h2f_bits(unsigned short u) {
    __half h = *reinterpret_cast<__half*>(&u);
    return __half2float(h);
}

// async 16B global->LDS (DMA path, no VGPR round-trip). LDS dest is
// wave-uniform base + lane*16 (HW rule) -- layout below is linear in lane order.
__device__ __forceinline__ void gload_lds16(const void* g, void* l) {
    __builtin_amdgcn_global_load_lds(
        (const __attribute__((address_space(1))) unsigned int*)g,
        (__attribute__((address_space(3))) unsigned int*)l, 16, 0, 0);
}

// ---------------- prep: W transposes (fp16), x cvt, csr=-1 init, deg hist ----
// deg is zeroed by a preceding hipMemsetAsync (stream-ordered).
__global__ void k_prep(const float* __restrict__ W1, unsigned short* __restrict__ W1T,
                       const float* __restrict__ W2, unsigned short* __restrict__ W2T,
                       const float* __restrict__ W3, unsigned short* __restrict__ W3T,
                       const float* __restrict__ x, unsigned short* __restrict__ xb,
                       int* __restrict__ csr, int Mcap,
                       const int* __restrict__ ei, int E, int* __restrict__ deg,
                       int DIN, int HC, int DOUT, int N)
{
    int i = blockIdx.x * blockDim.x + threadIdx.x;
    int n1 = DIN * HC;
    int n2 = n1 + HC * HC;
    int n3 = n2 + HC * DOUT;
    int n4 = n3 + N * DIN;
    int n5 = n4 + Mcap;
    int n6 = n5 + E;
    if (i < n1) {
        int k = i / HC, n = i - k * HC;
        W1T[n * DIN + k] = f2h_bits(W1[i]);
    } else if (i < n2) {
        int j = i - n1;
        int k = j / HC, n = j - k * HC;
        W2T[n * HC + k] = f2h_bits(W2[j]);
    } else if (i < n3) {
        int j = i - n2;
        int k = j / DOUT, n = j - k * DOUT;
        W3T[n * HC + k] = f2h_bits(W3[j]);
    } else if (i < n4) {
        int j = i - n3;
        xb[j] = f2h_bits(x[j]);
    } else if (i < n5) {
        csr[i - n4] = -1;           // pad sentinel
    } else if (i < n6) {
        atomicAdd(&deg[ei[E + (i - n5)]], 1);
    }
}

// scan of (deg+1) rounded up to multiple of 4 (padded segments)
__global__ void k_scan(const int* __restrict__ deg, int* __restrict__ off,
                       int* __restrict__ cur, int N) {
    __shared__ int sums[1024];
    int t = threadIdx.x;
    int chunk = (N + 1023) >> 10;
    int lo = t * chunk;
    int hi = lo + chunk; if (hi > N) hi = N;
    if (lo > N) lo = N;
    int s = 0;
    for (int i = lo; i < hi; ++i) s += (deg[i] + 4) & ~3;
    sums[t] = s;
    __syncthreads();
    for (int dd = 1; dd < 1024; dd <<= 1) {
        int v = (t >= dd) ? sums[t - dd] : 0;
        __syncthreads();
        sums[t] += v;
        __syncthreads();
    }
    int run = sums[t] - s;  // exclusive prefix
    for (int i = lo; i < hi; ++i) { off[i] = run; cur[i] = run; run += (deg[i] + 4) & ~3; }
    if (t == 1023) off[N] = run;
}
__global__ void k_fill(const int* __restrict__ ei, int E, int N,
                       int* cur, int* __restrict__ csr, int* __restrict__ dstarr) {
    int i = blockIdx.x * blockDim.x + threadIdx.x;
    if (i < E) {
        int s = ei[i], d = ei[E + i];
        int pos = atomicAdd(&cur[d], 1);
        csr[pos] = s;
        dstarr[pos] = d;
    } else if (i < E + N) {
        int nn = i - E;
        int pos = atomicAdd(&cur[nn], 1);
        csr[pos] = nn;
        dstarr[pos] = nn;
    }
}

// ---------------- GEMM (layer 3 / small-Nc path): register-only 64x64, fp16 --
// DOAL: fused attention-logit epilogue (valid only when tiles_n==1, i.e. the
// wave's 64 cols are ALL output cols; layer 3, H=1). Per row:
// al_s[row] = sum_col acc*a_src -> 4 FMA + shfl_xor reduce over the 16 r-lanes.
template <bool OUTH, bool DOAL>
__global__ __launch_bounds__(256) void k_gemm(
    const unsigned short* __restrict__ A, const unsigned short* __restrict__ BT,
    void* __restrict__ D, int M, int K, int Nc, int tiles_n,
    const float* __restrict__ asrc, const float* __restrict__ adst,
    float* __restrict__ als, float* __restrict__ ald)
{
    int wid = blockIdx.x * (blockDim.x >> 6) + (threadIdx.x >> 6);
    int tiles_m = (M + 63) >> 6;
    if (wid >= tiles_m * tiles_n) return;
    int lane = threadIdx.x & 63;
    int tm = wid / tiles_n, tn = wid - tm * tiles_n;
    int m0 = tm << 6, n0 = tn << 6;
    int r = lane & 15, q = lane >> 4;

    const unsigned short* Arow[4];
    const unsigned short* Brow[4];
#pragma unroll
    for (int i = 0; i < 4; ++i) {
        int row = m0 + 16 * i + r; row = row < M ? row : M - 1;
        Arow[i] = A + (size_t)row * K + q * 8;
        Brow[i] = BT + (size_t)(n0 + 16 * i + r) * K + q * 8;
    }

    f32x4 acc[4][4] = {};
    f16x8 a[4], b[4], a2[4], b2[4];
#pragma unroll
    for (int i = 0; i < 4; ++i) {
        a[i] = *(const f16x8*)(Arow[i]);
        b[i] = *(const f16x8*)(Brow[i]);
    }
    for (int k0 = 0; k0 < K; k0 += 32) {
        int kn = k0 + 32;
        if (kn < K) {
#pragma unroll
            for (int i = 0; i < 4; ++i) {
                a2[i] = *(const f16x8*)(Arow[i] + kn);
                b2[i] = *(const f16x8*)(Brow[i] + kn);
            }
        }
#pragma unroll
        for (int i = 0; i < 4; ++i)
#pragma unroll
            for (int j = 0; j < 4; ++j)
                acc[i][j] = __builtin_amdgcn_mfma_f32_16x16x32_f16(a[i], b[j], acc[i][j], 0, 0, 0);
        if (kn < K) {
#pragma unroll
            for (int i = 0; i < 4; ++i) { a[i] = a2[i]; b[i] = b2[i]; }
        }
    }
#pragma unroll
    for (int i = 0; i < 4; ++i) {
        int rowb = m0 + 16 * i + q * 4;
#pragma unroll
        for (int rr = 0; rr < 4; ++rr) {
            int row = rowb + rr;
            if (row < M) {
#pragma unroll
                for (int j = 0; j < 4; ++j) {
                    int col = n0 + 16 * j + r;
                    if (OUTH)
                        ((unsigned short*)D)[(size_t)row * Nc + col] = f2h_bits(acc[i][j][rr]);
                    else
                        ((float*)D)[(size_t)row * Nc + col] = acc[i][j][rr];
                }
            }
        }
    }
    if (DOAL) {
        float asl[4], adl[4];
#pragma unroll
        for (int j = 0; j < 4; ++j) { asl[j] = asrc[16 * j + r]; adl[j] = adst[16 * j + r]; }
#pragma unroll
        for (int i = 0; i < 4; ++i) {
#pragma unroll
            for (int rr = 0; rr < 4; ++rr) {
                float s = 0.f, d = 0.f;
#pragma unroll
                for (int j = 0; j < 4; ++j) {
                    s += acc[i][j][rr] * asl[j];
                    d += acc[i][j][rr] * adl[j];
                }
#pragma unroll
                for (int dd = 1; dd < 16; dd <<= 1) {
                    s += __shfl_xor(s, dd);
                    d += __shfl_xor(d, dd);
                }
                int row = m0 + 16 * i + q * 4 + rr;
                if (r == 0 && row < M) { als[row] = s; ald[row] = d; }
            }
        }
    }
}

// ---------------- GEMM (layers 1&2): m97-style 128x64 tile, LDS-staged, fp16 --
// 4 waves (2x2), wave tile 64x32, BK=32. Staging via global_load_lds width 16:
// per K-step each wave DMAs 3 KiB (2 A chunks + 1 B chunk, 1 KiB each, linear
// lane order), 2 barriers per K-step (the measured-874TF m97 schedule).
// BN=64 keeps the grid at (M/128)*(Nc/64)=632 blocks (~2.5/CU) -- at M=10000
// grid occupancy, not per-wave ILP, is the binding constraint.
__global__ __launch_bounds__(256) void k_gemm_lds(
    const unsigned short* __restrict__ A, const unsigned short* __restrict__ BT,
    unsigned short* __restrict__ D, int M, int K, int Nc, int tiles_n)
{
    __shared__ unsigned short As[128 * 32];   // 8 KiB
    __shared__ unsigned short Bs[64 * 32];    // 4 KiB
    int tm = blockIdx.x / tiles_n, tn = blockIdx.x - tm * tiles_n;
    int m0 = tm << 7, n0 = tn << 6;
    int tid = threadIdx.x;
    int w = tid >> 6, lane = tid & 63;
    int wr = w >> 1, wc = w & 1;
    int r = lane & 15, q = lane >> 4;

    // staging: chunk c = 16 tile-rows; lane l -> row c*16 + l/4, bytes (l&3)*16
    int lrow = lane >> 2;
    int lch = (lane & 3) * 8;                  // in fp16 elements
    int ga0 = m0 + w * 16 + lrow;       if (ga0 >= M) ga0 = M - 1;
    int ga1 = m0 + (w + 4) * 16 + lrow; if (ga1 >= M) ga1 = M - 1;
    const unsigned short* pa0 = A + (size_t)ga0 * K + lch;
    const unsigned short* pa1 = A + (size_t)ga1 * K + lch;
    const unsigned short* pb  = BT + (size_t)(n0 + w * 16 + lrow) * K + lch;
    unsigned short* lA0 = As + w * 512;        // wave-uniform LDS chunk bases
    unsigned short* lA1 = As + (w + 4) * 512;
    unsigned short* lB  = Bs + w * 512;

    const unsigned short* arp = As + (wr * 64 + r) * 32 + q * 8;
    const unsigned short* brp = Bs + (wc * 32 + r) * 32 + q * 8;

    f32x4 acc[4][2] = {};
    for (int k0 = 0; k0 < K; k0 += 32) {
        gload_lds16(pa0 + k0, lA0);
        gload_lds16(pa1 + k0, lA1);
        gload_lds16(pb + k0, lB);
        __syncthreads();                        // compiler drains vmcnt(0) here
        f16x8 a[4], b[2];
#pragma unroll
        for (int i = 0; i < 4; ++i) a[i] = *(const f16x8*)(arp + i * 16 * 32);
#pragma unroll
        for (int j = 0; j < 2; ++j) b[j] = *(const f16x8*)(brp + j * 16 * 32);
#pragma unroll
        for (int i = 0; i < 4; ++i)
#pragma unroll
            for (int j = 0; j < 2; ++j)
                acc[i][j] = __builtin_amdgcn_mfma_f32_16x16x32_f16(a[i], b[j], acc[i][j], 0, 0, 0);
        __syncthreads();                        // protect LDS before next stage
    }
#pragma unroll
    for (int i = 0; i < 4; ++i) {
        int rowb = m0 + wr * 64 + 16 * i + q * 4;
#pragma unroll
        for (int rr = 0; rr < 4; ++rr) {
            int row = rowb + rr;
            if (row < M) {
#pragma unroll
                for (int j = 0; j < 2; ++j) {
                    int col = n0 + wc * 32 + 16 * j + r;
                    D[(size_t)row * Nc + col] = f2h_bits(acc[i][j][rr]);
                }
            }
        }
    }
}

// ---------------- attention logits per node: al_s, al_d (fp16 h) ----------
template <int HCt, int Ht>
__global__ __launch_bounds__(256) void k_al(
    const unsigned short* __restrict__ h, const float* __restrict__ asrc,
    const float* __restrict__ adst,
    float* __restrict__ als, float* __restrict__ ald, int N)
{
    int wid = blockIdx.x * (blockDim.x >> 6) + (threadIdx.x >> 6);
    if (wid >= N) return;
    int lane = threadIdx.x & 63;
    const int CH = HCt / 64;
    const int Gs = 64 / Ht;  // lanes per head
    float s = 0.f, d = 0.f;
    if constexpr (CH == 8) {
        const uint4* hr = (const uint4*)(h + (size_t)wid * HCt) + lane;
        uint4 hv = *hr;
        unsigned wds[4] = {hv.x, hv.y, hv.z, hv.w};
        const f32x4* as4 = (const f32x4*)(asrc + lane * 8);
        const f32x4* ad4 = (const f32x4*)(adst + lane * 8);
        f32x4 av0 = as4[0], av1 = as4[1], dv0 = ad4[0], dv1 = ad4[1];
#pragma unroll
        for (int wv = 0; wv < 4; ++wv) {
            __half2 p = *reinterpret_cast<const __half2*>(&wds[wv]);
            float h0 = __low2float(p), h1 = __high2float(p);
            float a0 = (wv < 2) ? av0[2 * wv] : av1[2 * (wv - 2)];
            float a1 = (wv < 2) ? av0[2 * wv + 1] : av1[2 * (wv - 2) + 1];
            float d0 = (wv < 2) ? dv0[2 * wv] : dv1[2 * (wv - 2)];
            float d1 = (wv < 2) ? dv0[2 * wv + 1] : dv1[2 * (wv - 2) + 1];
            s = fmaf(h0, a0, s); s = fmaf(h1, a1, s);
            d = fmaf(h0, d0, d); d = fmaf(h1, d1, d);
        }
    } else {
        // CH == 1 (layer 3): one fp16 per lane
        float hv = h2f_bits(h[(size_t)wid * HCt + lane]);
        s = hv * asrc[lane];
        d = hv * adst[lane];
    }
#pragma unroll
    for (int dd = 1; dd < Gs; dd <<= 1) {
        s += __shfl_xor(s, dd);
        d += __shfl_xor(d, dd);
    }
    if ((lane & (Gs - 1)) == 0) {
        int hh = lane / Gs;
        als[wid * Ht + hh] = s;
        ald[wid * Ht + hh] = d;
    }
}

// ---------------- edge alpha, SoA head planes: alpha[h*Mcap + t] ----------
// pads (csr<0) get alpha=0 so aggr needs no bounds/tail logic
__global__ void k_alpha4(const float* __restrict__ als, const float* __restrict__ ald,
                         const int* __restrict__ csr, const int* __restrict__ dstarr,
                         const int* __restrict__ off, int N,
                         float* __restrict__ alpha, int Mcap)
{
    int t = blockIdx.x * blockDim.x + threadIdx.x;
    if (t >= off[N]) return;
    int s = csr[t];
    if (s < 0) {
#pragma unroll
        for (int h = 0; h < 4; ++h) alpha[(size_t)h * Mcap + t] = 0.f;
        return;
    }
    int d = dstarr[t];
    f32x4 a = *(const f32x4*)(als + (size_t)s * 4);
    f32x4 b = *(const f32x4*)(ald + (size_t)d * 4);
#pragma unroll
    for (int h = 0; h < 4; ++h) {
        float l = a[h] + b[h];
        l = l > 0.f ? l : 0.2f * l;
        alpha[(size_t)h * Mcap + t] = __expf(l);
    }
}

// ---------------- aggr HC=512 H=4, quad-edge, fp16 h + v_fma_mix ----------
// Wave = (node, head); 4 edge-groups x 16 lanes; each group consumes FOUR
// edges/iter: one int4 csr + one f32x4 alpha + 4x uint4 h rows (8 fp16 each).
// fp16 h turns unpack+fma (2 ops/ch) into one v_fma_mix_f32/ch -- aggr is
// VALU-issue-bound (R2 counters: VALUBusy 77%, HBM 14%), so this cuts the
// critical path ~30%. Segments padded to x4 (alpha=0 on pads) -> no tail
// logic. Slab-sequential grid (head-major) keeps h gather L2-resident/XCD.
// NOTE: no software pipeline — 8 waves per SIMD. Measured (r5, r8, r16):
// trading occupancy for per-wave ILP is net-negative here.
template <bool DOELU>
__global__ __launch_bounds__(256) void k_aggr4b(
    const unsigned short* __restrict__ h, const float* __restrict__ alpha,
    const int* __restrict__ off, const int* __restrict__ csr,
    const float* __restrict__ bias,
    unsigned short* __restrict__ outp, int N, int nodeBlocks, int Mcap)
{
    int head = blockIdx.x / nodeBlocks;
    int nb = blockIdx.x - head * nodeBlocks;
    int n = nb * 4 + (threadIdx.x >> 6);
    if (n >= N) return;
    int lane = threadIdx.x & 63;
    int g = lane >> 4;            // edge group 0..3
    int p = lane & 15;            // channel-lane within group
    int q0 = (off[n] >> 2) + g, q1 = off[n + 1] >> 2;

    float acc[8] = {};
    float den = 0.f;
    const unsigned short* hbase = h + head * 128 + p * 8;
    const int4* csr4 = (const int4*)csr;
    const f32x4* al4 = (const f32x4*)(alpha + (size_t)head * Mcap);

    auto fmaq = [&](float a, const uint4& hq) {
        unsigned wds[4] = {hq.x, hq.y, hq.z, hq.w};
#pragma unroll
        for (int wv = 0; wv < 4; ++wv) {
            __half2 pp = *reinterpret_cast<const __half2*>(&wds[wv]);
            acc[2 * wv]     = fmaf(a, __low2float(pp),  acc[2 * wv]);
            acc[2 * wv + 1] = fmaf(a, __high2float(pp), acc[2 * wv + 1]);
        }
    };

    for (int q = q0; q < q1; q += 4) {
        int4 cs = csr4[q];
        f32x4 av = al4[q];
        int c0 = cs.x < 0 ? 0 : cs.x;   // pads: alpha=0, clamp address
        int c1 = cs.y < 0 ? 0 : cs.y;
        int c2 = cs.z < 0 ? 0 : cs.z;
        int c3 = cs.w < 0 ? 0 : cs.w;
        uint4 h0 = *(const uint4*)(hbase + ((size_t)(unsigned)c0 << 9));
        uint4 h1 = *(const uint4*)(hbase + ((size_t)(unsigned)c1 << 9));
        uint4 h2 = *(const uint4*)(hbase + ((size_t)(unsigned)c2 << 9));
        uint4 h3 = *(const uint4*)(hbase + ((size_t)(unsigned)c3 << 9));
        den += (av[0] + av[1]) + (av[2] + av[3]);
        fmaq(av[0], h0);
        fmaq(av[1], h1);
        fmaq(av[2], h2);
        fmaq(av[3], h3);
    }

    den += __shfl_xor(den, 16);
    den += __shfl_xor(den, 32);
#pragma unroll
    for (int j = 0; j < 8; ++j) {
        acc[j] += __shfl_xor(acc[j], 16);
        acc[j] += __shfl_xor(acc[j], 32);
    }

    if (g == 0) {
        float inv = 1.f / den;
        int cb = head * 128 + p * 8;
        unsigned ww[4];
#pragma unroll
        for (int wv = 0; wv < 4; ++wv) {
            float v0 = acc[2 * wv] * inv + bias[cb + 2 * wv];
            float v1 = acc[2 * wv + 1] * inv + bias[cb + 2 * wv + 1];
            if (DOELU) {
                v0 = v0 > 0.f ? v0 : expm1f(v0);
                v1 = v1 > 0.f ? v1 : expm1f(v1);
            }
            ww[wv] = (unsigned)f2h_bits(v0) | ((unsigned)f2h_bits(v1) << 16);
        }
        uint4 o; o.x = ww[0]; o.y = ww[1]; o.z = ww[2]; o.w = ww[3];
        *((uint4*)(outp + (size_t)n * 512 + cb)) = o;
    }
}

// ---------------- layer-3 aggr (HC=64, H=1, fp16 h), quad-edge, inline exp
__global__ __launch_bounds__(256) void k_aggr1b(
    const unsigned short* __restrict__ h, const float* __restrict__ als,
    const float* __restrict__ aldv, const int* __restrict__ off,
    const int* __restrict__ csr, const float* __restrict__ bias,
    float* __restrict__ outp, int N)
{
    int n = blockIdx.x * (blockDim.x >> 6) + (threadIdx.x >> 6);
    if (n >= N) return;
    int lane = threadIdx.x & 63;
    int g = lane >> 4;
    int p = lane & 15;
    int q0 = (off[n] >> 2) + g, q1 = off[n + 1] >> 2;
    float aldh = aldv[n];

    float acc[4] = {};
    float den = 0.f;
    const unsigned short* hbase = h + p * 4;   // lane owns 4 fp16 (8B)
    const int4* csr4 = (const int4*)csr;

    auto aof = [&](int ss) -> float {
        int sc = ss < 0 ? 0 : ss;
        float l = als[sc] + aldh;
        l = l > 0.f ? l : 0.2f * l;
        float e = __expf(l);
        return ss < 0 ? 0.f : e;
    };
    auto fmaq = [&](float a, const uint2& hq) {
        den += a;
        __half2 p0 = *reinterpret_cast<const __half2*>(&hq.x);
        __half2 p1 = *reinterpret_cast<const __half2*>(&hq.y);
        acc[0] = fmaf(a, __low2float(p0),  acc[0]);
        acc[1] = fmaf(a, __high2float(p0), acc[1]);
        acc[2] = fmaf(a, __low2float(p1),  acc[2]);
        acc[3] = fmaf(a, __high2float(p1), acc[3]);
    };

    for (int q = q0; q < q1; q += 4) {
        int4 cs = csr4[q];
        float a0 = aof(cs.x), a1 = aof(cs.y), a2 = aof(cs.z), a3 = aof(cs.w);
        uint2 h0 = *(const uint2*)(hbase + ((size_t)(unsigned)(cs.x < 0 ? 0 : cs.x) << 6));
        uint2 h1 = *(const uint2*)(hbase + ((size_t)(unsigned)(cs.y < 0 ? 0 : cs.y) << 6));
        uint2 h2 = *(const uint2*)(hbase + ((size_t)(unsigned)(cs.z < 0 ? 0 : cs.z) << 6));
        uint2 h3 = *(const uint2*)(hbase + ((size_t)(unsigned)(cs.w < 0 ? 0 : cs.w) << 6));
        fmaq(a0, h0);
        fmaq(a1, h1);
        fmaq(a2, h2);
        fmaq(a3, h3);
    }

    den += __shfl_xor(den, 16);
    den += __shfl_xor(den, 32);
#pragma unroll
    for (int j = 0; j < 4; ++j) {
        acc[j] += __shfl_xor(acc[j], 16);
        acc[j] += __shfl_xor(acc[j], 32);
    }
    if (g == 0) {
        float inv = 1.f / den;
        f32x4 o;
#pragma unroll
        for (int j = 0; j < 4; ++j)
            o[j] = acc[j] * inv + bias[p * 4 + j];
        *((f32x4*)(outp + (size_t)n * 64 + p * 4)) = o;
    }
}

// --------------------------------------------------------------------------
extern "C" void kernel_launch(void* const* d_in, const int* in_sizes, int n_in,
                              void* d_out, int out_size, void* d_ws, size_t ws_size,
                              hipStream_t stream)
{
    const float* x   = (const float*)d_in[0];
    const int*   ei  = (const int*)d_in[1];
    const float* W1  = (const float*)d_in[2];
    const float* as1 = (const float*)d_in[3];
    const float* ad1 = (const float*)d_in[4];
    const float* b1  = (const float*)d_in[5];
    const float* W2  = (const float*)d_in[6];
    const float* as2 = (const float*)d_in[7];
    const float* ad2 = (const float*)d_in[8];
    const float* b2  = (const float*)d_in[9];
    const float* W3  = (const float*)d_in[10];
    const float* as3 = (const float*)d_in[11];
    const float* ad3 = (const float*)d_in[12];
    const float* b3  = (const float*)d_in[13];

    const int DIN = 256, HC = 512, DOUT = 64;
    int N = in_sizes[0] / DIN;
    int E = in_sizes[1] / 2;
    int Mcap = E + 4 * N;  // capacity for 4-padded CSR

    // workspace carve-up
    char* w = (char*)d_ws;
    auto alloc = [&](size_t bytes) -> char* {
        char* p = w;
        w += (bytes + 255) & ~(size_t)255;
        return p;
    };
    int* deg    = (int*)alloc((size_t)N * 4);
    int* cur    = (int*)alloc((size_t)N * 4);
    int* off    = (int*)alloc((size_t)(N + 1) * 4);
    int* csr    = (int*)alloc((size_t)Mcap * 4);
    int* dstarr = (int*)alloc((size_t)Mcap * 4);
    unsigned short* W1T = (unsigned short*)alloc((size_t)HC * DIN * 2);
    unsigned short* W2T = (unsigned short*)alloc((size_t)HC * HC * 2);
    unsigned short* W3T = (unsigned short*)alloc((size_t)DOUT * HC * 2);
    unsigned short* xb  = (unsigned short*)alloc((size_t)N * DIN * 2);
    unsigned short* act = (unsigned short*)alloc((size_t)N * HC * 2);
    unsigned short* hb  = (unsigned short*)alloc((size_t)N * HC * 2);
    unsigned short* hb3 = (unsigned short*)alloc((size_t)N * DOUT * 2);  // fp16 h (layer 3)
    float* als   = (float*)alloc((size_t)N * 4 * 4);
    float* ald   = (float*)alloc((size_t)N * 4 * 4);
    float* alpha = (float*)alloc((size_t)Mcap * 4 * 4);  // SoA: 4 planes of Mcap

    // ---- build: memset(deg) -> prep(+csr init+hist) -> scan -> fill ----
    hipMemsetAsync(deg, 0, (size_t)N * 4, stream);
    int prep_total = DIN * HC + HC * HC + HC * DOUT + N * DIN + Mcap + E;
    k_prep<<<(prep_total + 255) / 256, 256, 0, stream>>>(
        W1, W1T, W2, W2T, W3, W3T, x, xb, csr, Mcap, ei, E, deg, DIN, HC, DOUT, N);
    k_scan<<<1, 1024, 0, stream>>>(deg, off, cur, N);
    k_fill<<<(E + N + 255) / 256, 256, 0, stream>>>(ei, E, N, cur, csr, dstarr);

    int tiles_m = (N + 63) / 64;
    auto gemm_blocks = [&](int tn) { return (tiles_m * tn + 3) / 4; };
    int tm128 = (N + 127) / 128;
    int nwave_blocks = (N + 3) / 4;
    int nodeBlocks = (N + 3) / 4;
    int alpha_blocks = (Mcap + 255) / 256;

    // ---- layer 1 ----
    k_gemm_lds<<<tm128 * (HC / 64), 256, 0, stream>>>(xb, W1T, hb, N, DIN, HC, HC / 64);
    k_al<512, 4><<<nwave_blocks, 256, 0, stream>>>(hb, as1, ad1, als, ald, N);
    k_alpha4<<<alpha_blocks, 256, 0, stream>>>(als, ald, csr, dstarr, off, N, alpha, Mcap);
    k_aggr4b<true><<<4 * nodeBlocks, 256, 0, stream>>>(hb, alpha, off, csr, b1, act, N, nodeBlocks, Mcap);

    // ---- layer 2 ----
    k_gemm_lds<<<tm128 * (HC / 64), 256, 0, stream>>>(act, W2T, hb, N, HC, HC, HC / 64);
    k_al<512, 4><<<nwave_blocks, 256, 0, stream>>>(hb, as2, ad2, als, ald, N);
    k_alpha4<<<alpha_blocks, 256, 0, stream>>>(als, ald, csr, dstarr, off, N, alpha, Mcap);
    k_aggr4b<true><<<4 * nodeBlocks, 256, 0, stream>>>(hb, alpha, off, csr, b2, act, N, nodeBlocks, Mcap);

    // ---- layer 3 (fp16 h path; Nc=64, al fused into GEMM epilogue) ----
    k_gemm<true, true><<<gemm_blocks(1), 256, 0, stream>>>(
        act, W3T, hb3, N, HC, DOUT, 1, as3, ad3, als, ald);
    k_aggr1b<<<nwave_blocks, 256, 0, stream>>>(hb3, als, ald, off, csr, b3, (float*)d_out, N);
}

// Round 4
// 286.289 us; speedup vs baseline: 1.0535x; 1.0288x over previous
//
#include <hip/hip_runtime.h>
#include <hip/hip_fp16.h>

typedef _Float16 f16x8 __attribute__((ext_vector_type(8)));
typedef float f32x4 __attribute__((ext_vector_type(4)));

__device__ __forceinline__ unsigned short f2h_bits(float f) {
    __half h = __float2half(f);
    return *reinterpret_cast<unsigned short*>(&h);
}
__device__ __forceinline__ float h2f_bits(unsigned short u) {
    __half h = *reinterpret_cast<__half*>(&u);
    return __half2float(h);
}

// acc += a(f32) * f16_lo(hw)  -- one VOP3P v_fma_mix_f32
__device__ __forceinline__ void fma_mix_lo(float& acc, float a, unsigned hw) {
    asm("v_fma_mix_f32 %0, %1, %2, %0 op_sel_hi:[0,1,0]"
        : "+v"(acc) : "v"(a), "v"(hw));
}
// acc += a(f32) * f16_hi(hw)
__device__ __forceinline__ void fma_mix_hi(float& acc, float a, unsigned hw) {
    asm("v_fma_mix_f32 %0, %1, %2, %0 op_sel:[0,1,0] op_sel_hi:[0,1,0]"
        : "+v"(acc) : "v"(a), "v"(hw));
}

// async 16B global->LDS (DMA path, no VGPR round-trip). LDS dest is
// wave-uniform base + lane*16 (HW rule) -- layout below is linear in lane order.
__device__ __forceinline__ void gload_lds16(const void* g, void* l) {
    __builtin_amdgcn_global_load_lds(
        (const __attribute__((address_space(1))) unsigned int*)g,
        (__attribute__((address_space(3))) unsigned int*)l, 16, 0, 0);
}

// ---------------- prep: W transposes (fp16), x cvt, csr=-1 init, deg hist ----
// deg is zeroed by a preceding hipMemsetAsync (stream-ordered).
__global__ void k_prep(const float* __restrict__ W1, unsigned short* __restrict__ W1T,
                       const float* __restrict__ W2, unsigned short* __restrict__ W2T,
                       const float* __restrict__ W3, unsigned short* __restrict__ W3T,
                       const float* __restrict__ x, unsigned short* __restrict__ xb,
                       int* __restrict__ csr, int Mcap,
                       const int* __restrict__ ei, int E, int* __restrict__ deg,
                       int DIN, int HC, int DOUT, int N)
{
    int i = blockIdx.x * blockDim.x + threadIdx.x;
    int n1 = DIN * HC;
    int n2 = n1 + HC * HC;
    int n3 = n2 + HC * DOUT;
    int n4 = n3 + N * DIN;
    int n5 = n4 + Mcap;
    int n6 = n5 + E;
    if (i < n1) {
        int k = i / HC, n = i - k * HC;
        W1T[n * DIN + k] = f2h_bits(W1[i]);
    } else if (i < n2) {
        int j = i - n1;
        int k = j / HC, n = j - k * HC;
        W2T[n * HC + k] = f2h_bits(W2[j]);
    } else if (i < n3) {
        int j = i - n2;
        int k = j / DOUT, n = j - k * DOUT;
        W3T[n * HC + k] = f2h_bits(W3[j]);
    } else if (i < n4) {
        int j = i - n3;
        xb[j] = f2h_bits(x[j]);
    } else if (i < n5) {
        csr[i - n4] = -1;           // pad sentinel
    } else if (i < n6) {
        atomicAdd(&deg[ei[E + (i - n5)]], 1);
    }
}

// scan of (deg+1) rounded up to multiple of 4 (padded segments)
__global__ void k_scan(const int* __restrict__ deg, int* __restrict__ off,
                       int* __restrict__ cur, int N) {
    __shared__ int sums[1024];
    int t = threadIdx.x;
    int chunk = (N + 1023) >> 10;
    int lo = t * chunk;
    int hi = lo + chunk; if (hi > N) hi = N;
    if (lo > N) lo = N;
    int s = 0;
    for (int i = lo; i < hi; ++i) s += (deg[i] + 4) & ~3;
    sums[t] = s;
    __syncthreads();
    for (int dd = 1; dd < 1024; dd <<= 1) {
        int v = (t >= dd) ? sums[t - dd] : 0;
        __syncthreads();
        sums[t] += v;
        __syncthreads();
    }
    int run = sums[t] - s;  // exclusive prefix
    for (int i = lo; i < hi; ++i) { off[i] = run; cur[i] = run; run += (deg[i] + 4) & ~3; }
    if (t == 1023) off[N] = run;
}
__global__ void k_fill(const int* __restrict__ ei, int E, int N,
                       int* cur, int* __restrict__ csr, int* __restrict__ dstarr) {
    int i = blockIdx.x * blockDim.x + threadIdx.x;
    if (i < E) {
        int s = ei[i], d = ei[E + i];
        int pos = atomicAdd(&cur[d], 1);
        csr[pos] = s;
        dstarr[pos] = d;
    } else if (i < E + N) {
        int nn = i - E;
        int pos = atomicAdd(&cur[nn], 1);
        csr[pos] = nn;
        dstarr[pos] = nn;
    }
}

// ---------------- GEMM (layer 3 / small-Nc path): register-only 64x64, fp16 --
// DOAL: fused attention-logit epilogue (valid only when tiles_n==1, i.e. the
// wave's 64 cols are ALL output cols; layer 3, H=1). Per row:
// al_s[row] = sum_col acc*a_src -> 4 FMA + shfl_xor reduce over the 16 r-lanes.
template <bool OUTH, bool DOAL>
__global__ __launch_bounds__(256) void k_gemm(
    const unsigned short* __restrict__ A, const unsigned short* __restrict__ BT,
    void* __restrict__ D, int M, int K, int Nc, int tiles_n,
    const float* __restrict__ asrc, const float* __restrict__ adst,
    float* __restrict__ als, float* __restrict__ ald)
{
    int wid = blockIdx.x * (blockDim.x >> 6) + (threadIdx.x >> 6);
    int tiles_m = (M + 63) >> 6;
    if (wid >= tiles_m * tiles_n) return;
    int lane = threadIdx.x & 63;
    int tm = wid / tiles_n, tn = wid - tm * tiles_n;
    int m0 = tm << 6, n0 = tn << 6;
    int r = lane & 15, q = lane >> 4;

    const unsigned short* Arow[4];
    const unsigned short* Brow[4];
#pragma unroll
    for (int i = 0; i < 4; ++i) {
        int row = m0 + 16 * i + r; row = row < M ? row : M - 1;
        Arow[i] = A + (size_t)row * K + q * 8;
        Brow[i] = BT + (size_t)(n0 + 16 * i + r) * K + q * 8;
    }

    f32x4 acc[4][4] = {};
    f16x8 a[4], b[4], a2[4], b2[4];
#pragma unroll
    for (int i = 0; i < 4; ++i) {
        a[i] = *(const f16x8*)(Arow[i]);
        b[i] = *(const f16x8*)(Brow[i]);
    }
    for (int k0 = 0; k0 < K; k0 += 32) {
        int kn = k0 + 32;
        if (kn < K) {
#pragma unroll
            for (int i = 0; i < 4; ++i) {
                a2[i] = *(const f16x8*)(Arow[i] + kn);
                b2[i] = *(const f16x8*)(Brow[i] + kn);
            }
        }
#pragma unroll
        for (int i = 0; i < 4; ++i)
#pragma unroll
            for (int j = 0; j < 4; ++j)
                acc[i][j] = __builtin_amdgcn_mfma_f32_16x16x32_f16(a[i], b[j], acc[i][j], 0, 0, 0);
        if (kn < K) {
#pragma unroll
            for (int i = 0; i < 4; ++i) { a[i] = a2[i]; b[i] = b2[i]; }
        }
    }
#pragma unroll
    for (int i = 0; i < 4; ++i) {
        int rowb = m0 + 16 * i + q * 4;
#pragma unroll
        for (int rr = 0; rr < 4; ++rr) {
            int row = rowb + rr;
            if (row < M) {
#pragma unroll
                for (int j = 0; j < 4; ++j) {
                    int col = n0 + 16 * j + r;
                    if (OUTH)
                        ((unsigned short*)D)[(size_t)row * Nc + col] = f2h_bits(acc[i][j][rr]);
                    else
                        ((float*)D)[(size_t)row * Nc + col] = acc[i][j][rr];
                }
            }
        }
    }
    if (DOAL) {
        float asl[4], adl[4];
#pragma unroll
        for (int j = 0; j < 4; ++j) { asl[j] = asrc[16 * j + r]; adl[j] = adst[16 * j + r]; }
#pragma unroll
        for (int i = 0; i < 4; ++i) {
#pragma unroll
            for (int rr = 0; rr < 4; ++rr) {
                float s = 0.f, d = 0.f;
#pragma unroll
                for (int j = 0; j < 4; ++j) {
                    s += acc[i][j][rr] * asl[j];
                    d += acc[i][j][rr] * adl[j];
                }
#pragma unroll
                for (int dd = 1; dd < 16; dd <<= 1) {
                    s += __shfl_xor(s, dd);
                    d += __shfl_xor(d, dd);
                }
                int row = m0 + 16 * i + q * 4 + rr;
                if (r == 0 && row < M) { als[row] = s; ald[row] = d; }
            }
        }
    }
}

// ---------------- GEMM (layers 1&2): m97-style 128x64 tile, LDS-staged, fp16 --
// 4 waves (2x2), wave tile 64x32, BK=32. Staging via global_load_lds width 16:
// per K-step each wave DMAs 3 KiB (2 A chunks + 1 B chunk, 1 KiB each, linear
// lane order), 2 barriers per K-step (the measured-874TF m97 schedule).
// BN=64 keeps the grid at (M/128)*(Nc/64)=632 blocks (~2.5/CU) -- at M=10000
// grid occupancy, not per-wave ILP, is the binding constraint.
__global__ __launch_bounds__(256) void k_gemm_lds(
    const unsigned short* __restrict__ A, const unsigned short* __restrict__ BT,
    unsigned short* __restrict__ D, int M, int K, int Nc, int tiles_n)
{
    __shared__ unsigned short As[128 * 32];   // 8 KiB
    __shared__ unsigned short Bs[64 * 32];    // 4 KiB
    int tm = blockIdx.x / tiles_n, tn = blockIdx.x - tm * tiles_n;
    int m0 = tm << 7, n0 = tn << 6;
    int tid = threadIdx.x;
    int w = tid >> 6, lane = tid & 63;
    int wr = w >> 1, wc = w & 1;
    int r = lane & 15, q = lane >> 4;

    // staging: chunk c = 16 tile-rows; lane l -> row c*16 + l/4, bytes (l&3)*16
    int lrow = lane >> 2;
    int lch = (lane & 3) * 8;                  // in fp16 elements
    int ga0 = m0 + w * 16 + lrow;       if (ga0 >= M) ga0 = M - 1;
    int ga1 = m0 + (w + 4) * 16 + lrow; if (ga1 >= M) ga1 = M - 1;
    const unsigned short* pa0 = A + (size_t)ga0 * K + lch;
    const unsigned short* pa1 = A + (size_t)ga1 * K + lch;
    const unsigned short* pb  = BT + (size_t)(n0 + w * 16 + lrow) * K + lch;
    unsigned short* lA0 = As + w * 512;        // wave-uniform LDS chunk bases
    unsigned short* lA1 = As + (w + 4) * 512;
    unsigned short* lB  = Bs + w * 512;

    const unsigned short* arp = As + (wr * 64 + r) * 32 + q * 8;
    const unsigned short* brp = Bs + (wc * 32 + r) * 32 + q * 8;

    f32x4 acc[4][2] = {};
    for (int k0 = 0; k0 < K; k0 += 32) {
        gload_lds16(pa0 + k0, lA0);
        gload_lds16(pa1 + k0, lA1);
        gload_lds16(pb + k0, lB);
        __syncthreads();                        // compiler drains vmcnt(0) here
        f16x8 a[4], b[2];
#pragma unroll
        for (int i = 0; i < 4; ++i) a[i] = *(const f16x8*)(arp + i * 16 * 32);
#pragma unroll
        for (int j = 0; j < 2; ++j) b[j] = *(const f16x8*)(brp + j * 16 * 32);
#pragma unroll
        for (int i = 0; i < 4; ++i)
#pragma unroll
            for (int j = 0; j < 2; ++j)
                acc[i][j] = __builtin_amdgcn_mfma_f32_16x16x32_f16(a[i], b[j], acc[i][j], 0, 0, 0);
        __syncthreads();                        // protect LDS before next stage
    }
#pragma unroll
    for (int i = 0; i < 4; ++i) {
        int rowb = m0 + wr * 64 + 16 * i + q * 4;
#pragma unroll
        for (int rr = 0; rr < 4; ++rr) {
            int row = rowb + rr;
            if (row < M) {
#pragma unroll
                for (int j = 0; j < 2; ++j) {
                    int col = n0 + wc * 32 + 16 * j + r;
                    D[(size_t)row * Nc + col] = f2h_bits(acc[i][j][rr]);
                }
            }
        }
    }
}

// ---------------- attention logits per node: al_s, al_d (fp16 h) ----------
template <int HCt, int Ht>
__global__ __launch_bounds__(256) void k_al(
    const unsigned short* __restrict__ h, const float* __restrict__ asrc,
    const float* __restrict__ adst,
    float* __restrict__ als, float* __restrict__ ald, int N)
{
    int wid = blockIdx.x * (blockDim.x >> 6) + (threadIdx.x >> 6);
    if (wid >= N) return;
    int lane = threadIdx.x & 63;
    const int CH = HCt / 64;
    const int Gs = 64 / Ht;  // lanes per head
    float s = 0.f, d = 0.f;
    if constexpr (CH == 8) {
        const uint4* hr = (const uint4*)(h + (size_t)wid * HCt) + lane;
        uint4 hv = *hr;
        unsigned wds[4] = {hv.x, hv.y, hv.z, hv.w};
        const f32x4* as4 = (const f32x4*)(asrc + lane * 8);
        const f32x4* ad4 = (const f32x4*)(adst + lane * 8);
        f32x4 av0 = as4[0], av1 = as4[1], dv0 = ad4[0], dv1 = ad4[1];
#pragma unroll
        for (int wv = 0; wv < 4; ++wv) {
            float a0 = (wv < 2) ? av0[2 * wv] : av1[2 * (wv - 2)];
            float a1 = (wv < 2) ? av0[2 * wv + 1] : av1[2 * (wv - 2) + 1];
            float d0 = (wv < 2) ? dv0[2 * wv] : dv1[2 * (wv - 2)];
            float d1 = (wv < 2) ? dv0[2 * wv + 1] : dv1[2 * (wv - 2) + 1];
            fma_mix_lo(s, a0, wds[wv]); fma_mix_hi(s, a1, wds[wv]);
            fma_mix_lo(d, d0, wds[wv]); fma_mix_hi(d, d1, wds[wv]);
        }
    } else {
        // CH == 1 (layer 3): one fp16 per lane
        float hv = h2f_bits(h[(size_t)wid * HCt + lane]);
        s = hv * asrc[lane];
        d = hv * adst[lane];
    }
#pragma unroll
    for (int dd = 1; dd < Gs; dd <<= 1) {
        s += __shfl_xor(s, dd);
        d += __shfl_xor(d, dd);
    }
    if ((lane & (Gs - 1)) == 0) {
        int hh = lane / Gs;
        als[wid * Ht + hh] = s;
        ald[wid * Ht + hh] = d;
    }
}

// ---------------- edge alpha, SoA head planes: alpha[h*Mcap + t] ----------
// pads (csr<0) get alpha=0 so aggr needs no bounds/tail logic
__global__ void k_alpha4(const float* __restrict__ als, const float* __restrict__ ald,
                         const int* __restrict__ csr, const int* __restrict__ dstarr,
                         const int* __restrict__ off, int N,
                         float* __restrict__ alpha, int Mcap)
{
    int t = blockIdx.x * blockDim.x + threadIdx.x;
    if (t >= off[N]) return;
    int s = csr[t];
    if (s < 0) {
#pragma unroll
        for (int h = 0; h < 4; ++h) alpha[(size_t)h * Mcap + t] = 0.f;
        return;
    }
    int d = dstarr[t];
    f32x4 a = *(const f32x4*)(als + (size_t)s * 4);
    f32x4 b = *(const f32x4*)(ald + (size_t)d * 4);
#pragma unroll
    for (int h = 0; h < 4; ++h) {
        float l = a[h] + b[h];
        l = l > 0.f ? l : 0.2f * l;
        alpha[(size_t)h * Mcap + t] = __expf(l);
    }
}

// ---------------- aggr HC=512 H=4, quad-edge, fp16 h + forced v_fma_mix ---
// Wave = (node, head); 4 edge-groups x 16 lanes; each group consumes FOUR
// edges/iter: one int4 csr + one f32x4 alpha + 4x uint4 h rows (8 fp16 each).
// Inline-asm v_fma_mix_f32 does alpha(f32)*h(f16)+acc in ONE op/channel --
// aggr is VALU-issue-bound (R2: VALUBusy 77%, HBM 14%); R3 showed the
// compiler won't form mix from fmaf+cvt on its own. Gather addresses are
// uniform-base + 32-bit byte offset so the compiler can emit saddr-form
// global_load_dwordx4 (1 VALU addr op instead of 64-bit pointer math).
// Segments padded to x4 (alpha=0 on pads) -> no tail logic. Slab-sequential
// grid (head-major) keeps h gather L2-resident/XCD.
template <bool DOELU>
__global__ __launch_bounds__(256) void k_aggr4b(
    const unsigned short* __restrict__ h, const float* __restrict__ alpha,
    const int* __restrict__ off, const int* __restrict__ csr,
    const float* __restrict__ bias,
    unsigned short* __restrict__ outp, int N, int nodeBlocks, int Mcap)
{
    int head = blockIdx.x / nodeBlocks;
    int nb = blockIdx.x - head * nodeBlocks;
    int n = nb * 4 + (threadIdx.x >> 6);
    if (n >= N) return;
    int lane = threadIdx.x & 63;
    int g = lane >> 4;            // edge group 0..3
    int p = lane & 15;            // channel-lane within group
    int q0 = (off[n] >> 2) + g, q1 = off[n + 1] >> 2;

    float acc[8] = {};
    float den = 0.f;
    const char* hB = (const char*)h;
    const unsigned offp = (unsigned)(head * 256 + p * 16);   // bytes within row
    const int4* csr4 = (const int4*)csr;
    const f32x4* al4 = (const f32x4*)(alpha + (size_t)head * Mcap);

    auto fmaq = [&](float a, const uint4& hq) {
        unsigned wds[4] = {hq.x, hq.y, hq.z, hq.w};
#pragma unroll
        for (int wv = 0; wv < 4; ++wv) {
            fma_mix_lo(acc[2 * wv],     a, wds[wv]);
            fma_mix_hi(acc[2 * wv + 1], a, wds[wv]);
        }
    };

    for (int q = q0; q < q1; q += 4) {
        int4 cs = csr4[q];
        f32x4 av = al4[q];
        int c0 = cs.x < 0 ? 0 : cs.x;   // pads: alpha=0, clamp address
        int c1 = cs.y < 0 ? 0 : cs.y;
        int c2 = cs.z < 0 ? 0 : cs.z;
        int c3 = cs.w < 0 ? 0 : cs.w;
        uint4 h0 = *(const uint4*)(hB + (size_t)((((unsigned)c0) << 10) + offp));
        uint4 h1 = *(const uint4*)(hB + (size_t)((((unsigned)c1) << 10) + offp));
        uint4 h2 = *(const uint4*)(hB + (size_t)((((unsigned)c2) << 10) + offp));
        uint4 h3 = *(const uint4*)(hB + (size_t)((((unsigned)c3) << 10) + offp));
        den += (av[0] + av[1]) + (av[2] + av[3]);
        fmaq(av[0], h0);
        fmaq(av[1], h1);
        fmaq(av[2], h2);
        fmaq(av[3], h3);
    }

    den += __shfl_xor(den, 16);
    den += __shfl_xor(den, 32);
#pragma unroll
    for (int j = 0; j < 8; ++j) {
        acc[j] += __shfl_xor(acc[j], 16);
        acc[j] += __shfl_xor(acc[j], 32);
    }

    if (g == 0) {
        float inv = 1.f / den;
        int cb = head * 128 + p * 8;
        unsigned ww[4];
#pragma unroll
        for (int wv = 0; wv < 4; ++wv) {
            float v0 = acc[2 * wv] * inv + bias[cb + 2 * wv];
            float v1 = acc[2 * wv + 1] * inv + bias[cb + 2 * wv + 1];
            if (DOELU) {
                v0 = v0 > 0.f ? v0 : expm1f(v0);
                v1 = v1 > 0.f ? v1 : expm1f(v1);
            }
            ww[wv] = (unsigned)f2h_bits(v0) | ((unsigned)f2h_bits(v1) << 16);
        }
        uint4 o; o.x = ww[0]; o.y = ww[1]; o.z = ww[2]; o.w = ww[3];
        *((uint4*)(outp + (size_t)n * 512 + cb)) = o;
    }
}

// ---------------- layer-3 aggr (HC=64, H=1, fp16 h), quad-edge, inline exp
__global__ __launch_bounds__(256) void k_aggr1b(
    const unsigned short* __restrict__ h, const float* __restrict__ als,
    const float* __restrict__ aldv, const int* __restrict__ off,
    const int* __restrict__ csr, const float* __restrict__ bias,
    float* __restrict__ outp, int N)
{
    int n = blockIdx.x * (blockDim.x >> 6) + (threadIdx.x >> 6);
    if (n >= N) return;
    int lane = threadIdx.x & 63;
    int g = lane >> 4;
    int p = lane & 15;
    int q0 = (off[n] >> 2) + g, q1 = off[n + 1] >> 2;
    float aldh = aldv[n];

    float acc[4] = {};
    float den = 0.f;
    const char* hB = (const char*)h;
    const unsigned offp = (unsigned)(p * 8);   // bytes; lane owns 4 fp16 (8B)
    const int4* csr4 = (const int4*)csr;

    auto aof = [&](int ss) -> float {
        int sc = ss < 0 ? 0 : ss;
        float l = als[sc] + aldh;
        l = l > 0.f ? l : 0.2f * l;
        float e = __expf(l);
        return ss < 0 ? 0.f : e;
    };
    auto fmaq = [&](float a, const uint2& hq) {
        den += a;
        fma_mix_lo(acc[0], a, hq.x);
        fma_mix_hi(acc[1], a, hq.x);
        fma_mix_lo(acc[2], a, hq.y);
        fma_mix_hi(acc[3], a, hq.y);
    };

    for (int q = q0; q < q1; q += 4) {
        int4 cs = csr4[q];
        float a0 = aof(cs.x), a1 = aof(cs.y), a2 = aof(cs.z), a3 = aof(cs.w);
        uint2 h0 = *(const uint2*)(hB + (size_t)((((unsigned)(cs.x < 0 ? 0 : cs.x)) << 7) + offp));
        uint2 h1 = *(const uint2*)(hB + (size_t)((((unsigned)(cs.y < 0 ? 0 : cs.y)) << 7) + offp));
        uint2 h2 = *(const uint2*)(hB + (size_t)((((unsigned)(cs.z < 0 ? 0 : cs.z)) << 7) + offp));
        uint2 h3 = *(const uint2*)(hB + (size_t)((((unsigned)(cs.w < 0 ? 0 : cs.w)) << 7) + offp));
        fmaq(a0, h0);
        fmaq(a1, h1);
        fmaq(a2, h2);
        fmaq(a3, h3);
    }

    den += __shfl_xor(den, 16);
    den += __shfl_xor(den, 32);
#pragma unroll
    for (int j = 0; j < 4; ++j) {
        acc[j] += __shfl_xor(acc[j], 16);
        acc[j] += __shfl_xor(acc[j], 32);
    }
    if (g == 0) {
        float inv = 1.f / den;
        f32x4 o;
#pragma unroll
        for (int j = 0; j < 4; ++j)
            o[j] = acc[j] * inv + bias[p * 4 + j];
        *((f32x4*)(outp + (size_t)n * 64 + p * 4)) = o;
    }
}

// --------------------------------------------------------------------------
extern "C" void kernel_launch(void* const* d_in, const int* in_sizes, int n_in,
                              void* d_out, int out_size, void* d_ws, size_t ws_size,
                              hipStream_t stream)
{
    const float* x   = (const float*)d_in[0];
    const int*   ei  = (const int*)d_in[1];
    const float* W1  = (const float*)d_in[2];
    const float* as1 = (const float*)d_in[3];
    const float* ad1 = (const float*)d_in[4];
    const float* b1  = (const float*)d_in[5];
    const float* W2  = (const float*)d_in[6];
    const float* as2 = (const float*)d_in[7];
    const float* ad2 = (const float*)d_in[8];
    const float* b2  = (const float*)d_in[9];
    const float* W3  = (const float*)d_in[10];
    const float* as3 = (const float*)d_in[11];
    const float* ad3 = (const float*)d_in[12];
    const float* b3  = (const float*)d_in[13];

    const int DIN = 256, HC = 512, DOUT = 64;
    int N = in_sizes[0] / DIN;
    int E = in_sizes[1] / 2;
    int Mcap = E + 4 * N;  // capacity for 4-padded CSR

    // workspace carve-up
    char* w = (char*)d_ws;
    auto alloc = [&](size_t bytes) -> char* {
        char* p = w;
        w += (bytes + 255) & ~(size_t)255;
        return p;
    };
    int* deg    = (int*)alloc((size_t)N * 4);
    int* cur    = (int*)alloc((size_t)N * 4);
    int* off    = (int*)alloc((size_t)(N + 1) * 4);
    int* csr    = (int*)alloc((size_t)Mcap * 4);
    int* dstarr = (int*)alloc((size_t)Mcap * 4);
    unsigned short* W1T = (unsigned short*)alloc((size_t)HC * DIN * 2);
    unsigned short* W2T = (unsigned short*)alloc((size_t)HC * HC * 2);
    unsigned short* W3T = (unsigned short*)alloc((size_t)DOUT * HC * 2);
    unsigned short* xb  = (unsigned short*)alloc((size_t)N * DIN * 2);
    unsigned short* act = (unsigned short*)alloc((size_t)N * HC * 2);
    unsigned short* hb  = (unsigned short*)alloc((size_t)N * HC * 2);
    unsigned short* hb3 = (unsigned short*)alloc((size_t)N * DOUT * 2);  // fp16 h (layer 3)
    float* als   = (float*)alloc((size_t)N * 4 * 4);
    float* ald   = (float*)alloc((size_t)N * 4 * 4);
    float* alpha = (float*)alloc((size_t)Mcap * 4 * 4);  // SoA: 4 planes of Mcap

    // ---- build: memset(deg) -> prep(+csr init+hist) -> scan -> fill ----
    hipMemsetAsync(deg, 0, (size_t)N * 4, stream);
    int prep_total = DIN * HC + HC * HC + HC * DOUT + N * DIN + Mcap + E;
    k_prep<<<(prep_total + 255) / 256, 256, 0, stream>>>(
        W1, W1T, W2, W2T, W3, W3T, x, xb, csr, Mcap, ei, E, deg, DIN, HC, DOUT, N);
    k_scan<<<1, 1024, 0, stream>>>(deg, off, cur, N);
    k_fill<<<(E + N + 255) / 256, 256, 0, stream>>>(ei, E, N, cur, csr, dstarr);

    int tiles_m = (N + 63) / 64;
    auto gemm_blocks = [&](int tn) { return (tiles_m * tn + 3) / 4; };
    int tm128 = (N + 127) / 128;
    int nwave_blocks = (N + 3) / 4;
    int nodeBlocks = (N + 3) / 4;
    int alpha_blocks = (Mcap + 255) / 256;

    // ---- layer 1 ----
    k_gemm_lds<<<tm128 * (HC / 64), 256, 0, stream>>>(xb, W1T, hb, N, DIN, HC, HC / 64);
    k_al<512, 4><<<nwave_blocks, 256, 0, stream>>>(hb, as1, ad1, als, ald, N);
    k_alpha4<<<alpha_blocks, 256, 0, stream>>>(als, ald, csr, dstarr, off, N, alpha, Mcap);
    k_aggr4b<true><<<4 * nodeBlocks, 256, 0, stream>>>(hb, alpha, off, csr, b1, act, N, nodeBlocks, Mcap);

    // ---- layer 2 ----
    k_gemm_lds<<<tm128 * (HC / 64), 256, 0, stream>>>(act, W2T, hb, N, HC, HC, HC / 64);
    k_al<512, 4><<<nwave_blocks, 256, 0, stream>>>(hb, as2, ad2, als, ald, N);
    k_alpha4<<<alpha_blocks, 256, 0, stream>>>(als, ald, csr, dstarr, off, N, alpha, Mcap);
    k_aggr4b<true><<<4 * nodeBlocks, 256, 0, stream>>>(hb, alpha, off, csr, b2, act, N, nodeBlocks, Mcap);

    // ---- layer 3 (fp16 h path; Nc=64, al fused into GEMM epilogue) ----
    k_gemm<true, true><<<gemm_blocks(1), 256, 0, stream>>>(
        act, W3T, hb3, N, HC, DOUT, 1, as3, ad3, als, ald);
    k_aggr1b<<<nwave_blocks, 256, 0, stream>>>(hb3, als, ald, off, csr, b3, (float*)d_out, N);
}

// Round 5
// 283.864 us; speedup vs baseline: 1.0625x; 1.0085x over previous
//
#include <hip/hip_runtime.h>
#include <hip/hip_fp16.h>

typedef _Float16 f16x8 __attribute__((ext_vector_type(8)));
typedef float f32x4 __attribute__((ext_vector_type(4)));

__device__ __forceinline__ unsigned short f2h_bits(float f) {
    __half h = __float2half(f);
    return *reinterpret_cast<unsigned short*>(&h);
}
__device__ __forceinline__ float h2f_bits(unsigned short u) {
    __half h = *reinterpret_cast<__half*>(&u);
    return __half2float(h);
}

// acc += a(f32) * f16_lo(hw)  -- one VOP3P v_fma_mix_f32
__device__ __forceinline__ void fma_mix_lo(float& acc, float a, unsigned hw) {
    asm("v_fma_mix_f32 %0, %1, %2, %0 op_sel_hi:[0,1,0]"
        : "+v"(acc) : "v"(a), "v"(hw));
}
// acc += a(f32) * f16_hi(hw)
__device__ __forceinline__ void fma_mix_hi(float& acc, float a, unsigned hw) {
    asm("v_fma_mix_f32 %0, %1, %2, %0 op_sel:[0,1,0] op_sel_hi:[0,1,0]"
        : "+v"(acc) : "v"(a), "v"(hw));
}

// async 16B global->LDS (DMA path, no VGPR round-trip). LDS dest is
// wave-uniform base + lane*16 (HW rule) -- layout below is linear in lane order.
__device__ __forceinline__ void gload_lds16(const void* g, void* l) {
    __builtin_amdgcn_global_load_lds(
        (const __attribute__((address_space(1))) unsigned int*)g,
        (__attribute__((address_space(3))) unsigned int*)l, 16, 0, 0);
}

// ---------------- prep: W transposes (fp16), x cvt, csr=-1 init, deg hist ----
// deg is zeroed by a preceding hipMemsetAsync (stream-ordered).
__global__ void k_prep(const float* __restrict__ W1, unsigned short* __restrict__ W1T,
                       const float* __restrict__ W2, unsigned short* __restrict__ W2T,
                       const float* __restrict__ W3, unsigned short* __restrict__ W3T,
                       const float* __restrict__ x, unsigned short* __restrict__ xb,
                       int* __restrict__ csr, int Mcap,
                       const int* __restrict__ ei, int E, int* __restrict__ deg,
                       int DIN, int HC, int DOUT, int N)
{
    int i = blockIdx.x * blockDim.x + threadIdx.x;
    int n1 = DIN * HC;
    int n2 = n1 + HC * HC;
    int n3 = n2 + HC * DOUT;
    int n4 = n3 + N * DIN;
    int n5 = n4 + Mcap;
    int n6 = n5 + E;
    if (i < n1) {
        int k = i / HC, n = i - k * HC;
        W1T[n * DIN + k] = f2h_bits(W1[i]);
    } else if (i < n2) {
        int j = i - n1;
        int k = j / HC, n = j - k * HC;
        W2T[n * HC + k] = f2h_bits(W2[j]);
    } else if (i < n3) {
        int j = i - n2;
        int k = j / DOUT, n = j - k * DOUT;
        W3T[n * HC + k] = f2h_bits(W3[j]);
    } else if (i < n4) {
        int j = i - n3;
        xb[j] = f2h_bits(x[j]);
    } else if (i < n5) {
        csr[i - n4] = -1;           // pad sentinel
    } else if (i < n6) {
        atomicAdd(&deg[ei[E + (i - n5)]], 1);
    }
}

// scan of (deg+1) rounded up to multiple of 4 (padded segments)
__global__ void k_scan(const int* __restrict__ deg, int* __restrict__ off,
                       int* __restrict__ cur, int N) {
    __shared__ int sums[1024];
    int t = threadIdx.x;
    int chunk = (N + 1023) >> 10;
    int lo = t * chunk;
    int hi = lo + chunk; if (hi > N) hi = N;
    if (lo > N) lo = N;
    int s = 0;
    for (int i = lo; i < hi; ++i) s += (deg[i] + 4) & ~3;
    sums[t] = s;
    __syncthreads();
    for (int dd = 1; dd < 1024; dd <<= 1) {
        int v = (t >= dd) ? sums[t - dd] : 0;
        __syncthreads();
        sums[t] += v;
        __syncthreads();
    }
    int run = sums[t] - s;  // exclusive prefix
    for (int i = lo; i < hi; ++i) { off[i] = run; cur[i] = run; run += (deg[i] + 4) & ~3; }
    if (t == 1023) off[N] = run;
}
__global__ void k_fill(const int* __restrict__ ei, int E, int N,
                       int* cur, int* __restrict__ csr) {
    int i = blockIdx.x * blockDim.x + threadIdx.x;
    if (i < E) {
        int s = ei[i], d = ei[E + i];
        int pos = atomicAdd(&cur[d], 1);
        csr[pos] = s;
    } else if (i < E + N) {
        int nn = i - E;
        int pos = atomicAdd(&cur[nn], 1);
        csr[pos] = nn;
    }
}

// ---------------- GEMM (layer 3 / small-Nc path): register-only 64x64, fp16 --
// DOAL: fused attention-logit epilogue (valid only when tiles_n==1, i.e. the
// wave's 64 cols are ALL output cols; layer 3, H=1). Per row:
// al_s[row] = sum_col acc*a_src -> 4 FMA + shfl_xor reduce over the 16 r-lanes.
template <bool OUTH, bool DOAL>
__global__ __launch_bounds__(256) void k_gemm(
    const unsigned short* __restrict__ A, const unsigned short* __restrict__ BT,
    void* __restrict__ D, int M, int K, int Nc, int tiles_n,
    const float* __restrict__ asrc, const float* __restrict__ adst,
    float* __restrict__ als, float* __restrict__ ald)
{
    int wid = blockIdx.x * (blockDim.x >> 6) + (threadIdx.x >> 6);
    int tiles_m = (M + 63) >> 6;
    if (wid >= tiles_m * tiles_n) return;
    int lane = threadIdx.x & 63;
    int tm = wid / tiles_n, tn = wid - tm * tiles_n;
    int m0 = tm << 6, n0 = tn << 6;
    int r = lane & 15, q = lane >> 4;

    const unsigned short* Arow[4];
    const unsigned short* Brow[4];
#pragma unroll
    for (int i = 0; i < 4; ++i) {
        int row = m0 + 16 * i + r; row = row < M ? row : M - 1;
        Arow[i] = A + (size_t)row * K + q * 8;
        Brow[i] = BT + (size_t)(n0 + 16 * i + r) * K + q * 8;
    }

    f32x4 acc[4][4] = {};
    f16x8 a[4], b[4], a2[4], b2[4];
#pragma unroll
    for (int i = 0; i < 4; ++i) {
        a[i] = *(const f16x8*)(Arow[i]);
        b[i] = *(const f16x8*)(Brow[i]);
    }
    for (int k0 = 0; k0 < K; k0 += 32) {
        int kn = k0 + 32;
        if (kn < K) {
#pragma unroll
            for (int i = 0; i < 4; ++i) {
                a2[i] = *(const f16x8*)(Arow[i] + kn);
                b2[i] = *(const f16x8*)(Brow[i] + kn);
            }
        }
#pragma unroll
        for (int i = 0; i < 4; ++i)
#pragma unroll
            for (int j = 0; j < 4; ++j)
                acc[i][j] = __builtin_amdgcn_mfma_f32_16x16x32_f16(a[i], b[j], acc[i][j], 0, 0, 0);
        if (kn < K) {
#pragma unroll
            for (int i = 0; i < 4; ++i) { a[i] = a2[i]; b[i] = b2[i]; }
        }
    }
#pragma unroll
    for (int i = 0; i < 4; ++i) {
        int rowb = m0 + 16 * i + q * 4;
#pragma unroll
        for (int rr = 0; rr < 4; ++rr) {
            int row = rowb + rr;
            if (row < M) {
#pragma unroll
                for (int j = 0; j < 4; ++j) {
                    int col = n0 + 16 * j + r;
                    if (OUTH)
                        ((unsigned short*)D)[(size_t)row * Nc + col] = f2h_bits(acc[i][j][rr]);
                    else
                        ((float*)D)[(size_t)row * Nc + col] = acc[i][j][rr];
                }
            }
        }
    }
    if (DOAL) {
        float asl[4], adl[4];
#pragma unroll
        for (int j = 0; j < 4; ++j) { asl[j] = asrc[16 * j + r]; adl[j] = adst[16 * j + r]; }
#pragma unroll
        for (int i = 0; i < 4; ++i) {
#pragma unroll
            for (int rr = 0; rr < 4; ++rr) {
                float s = 0.f, d = 0.f;
#pragma unroll
                for (int j = 0; j < 4; ++j) {
                    s += acc[i][j][rr] * asl[j];
                    d += acc[i][j][rr] * adl[j];
                }
#pragma unroll
                for (int dd = 1; dd < 16; dd <<= 1) {
                    s += __shfl_xor(s, dd);
                    d += __shfl_xor(d, dd);
                }
                int row = m0 + 16 * i + q * 4 + rr;
                if (r == 0 && row < M) { als[row] = s; ald[row] = d; }
            }
        }
    }
}

// ---------------- GEMM (layers 1&2): m97-style 128x64 tile, LDS-staged, fp16 --
// 4 waves (2x2), wave tile 64x32, BK=32. Staging via global_load_lds width 16:
// per K-step each wave DMAs 3 KiB (2 A chunks + 1 B chunk, 1 KiB each, linear
// lane order), 2 barriers per K-step (the measured-874TF m97 schedule).
// BN=64 keeps the grid at (M/128)*(Nc/64)=632 blocks (~2.5/CU) -- at M=10000
// grid occupancy, not per-wave ILP, is the binding constraint.
__global__ __launch_bounds__(256) void k_gemm_lds(
    const unsigned short* __restrict__ A, const unsigned short* __restrict__ BT,
    unsigned short* __restrict__ D, int M, int K, int Nc, int tiles_n)
{
    __shared__ unsigned short As[128 * 32];   // 8 KiB
    __shared__ unsigned short Bs[64 * 32];    // 4 KiB
    int tm = blockIdx.x / tiles_n, tn = blockIdx.x - tm * tiles_n;
    int m0 = tm << 7, n0 = tn << 6;
    int tid = threadIdx.x;
    int w = tid >> 6, lane = tid & 63;
    int wr = w >> 1, wc = w & 1;
    int r = lane & 15, q = lane >> 4;

    // staging: chunk c = 16 tile-rows; lane l -> row c*16 + l/4, bytes (l&3)*16
    int lrow = lane >> 2;
    int lch = (lane & 3) * 8;                  // in fp16 elements
    int ga0 = m0 + w * 16 + lrow;       if (ga0 >= M) ga0 = M - 1;
    int ga1 = m0 + (w + 4) * 16 + lrow; if (ga1 >= M) ga1 = M - 1;
    const unsigned short* pa0 = A + (size_t)ga0 * K + lch;
    const unsigned short* pa1 = A + (size_t)ga1 * K + lch;
    const unsigned short* pb  = BT + (size_t)(n0 + w * 16 + lrow) * K + lch;
    unsigned short* lA0 = As + w * 512;        // wave-uniform LDS chunk bases
    unsigned short* lA1 = As + (w + 4) * 512;
    unsigned short* lB  = Bs + w * 512;

    const unsigned short* arp = As + (wr * 64 + r) * 32 + q * 8;
    const unsigned short* brp = Bs + (wc * 32 + r) * 32 + q * 8;

    f32x4 acc[4][2] = {};
    for (int k0 = 0; k0 < K; k0 += 32) {
        gload_lds16(pa0 + k0, lA0);
        gload_lds16(pa1 + k0, lA1);
        gload_lds16(pb + k0, lB);
        __syncthreads();                        // compiler drains vmcnt(0) here
        f16x8 a[4], b[2];
#pragma unroll
        for (int i = 0; i < 4; ++i) a[i] = *(const f16x8*)(arp + i * 16 * 32);
#pragma unroll
        for (int j = 0; j < 2; ++j) b[j] = *(const f16x8*)(brp + j * 16 * 32);
#pragma unroll
        for (int i = 0; i < 4; ++i)
#pragma unroll
            for (int j = 0; j < 2; ++j)
                acc[i][j] = __builtin_amdgcn_mfma_f32_16x16x32_f16(a[i], b[j], acc[i][j], 0, 0, 0);
        __syncthreads();                        // protect LDS before next stage
    }
#pragma unroll
    for (int i = 0; i < 4; ++i) {
        int rowb = m0 + wr * 64 + 16 * i + q * 4;
#pragma unroll
        for (int rr = 0; rr < 4; ++rr) {
            int row = rowb + rr;
            if (row < M) {
#pragma unroll
                for (int j = 0; j < 2; ++j) {
                    int col = n0 + wc * 32 + 16 * j + r;
                    D[(size_t)row * Nc + col] = f2h_bits(acc[i][j][rr]);
                }
            }
        }
    }
}

// ---------------- attention logits per node: al_s, al_d (fp16 h) ----------
template <int HCt, int Ht>
__global__ __launch_bounds__(256) void k_al(
    const unsigned short* __restrict__ h, const float* __restrict__ asrc,
    const float* __restrict__ adst,
    float* __restrict__ als, float* __restrict__ ald, int N)
{
    int wid = blockIdx.x * (blockDim.x >> 6) + (threadIdx.x >> 6);
    if (wid >= N) return;
    int lane = threadIdx.x & 63;
    const int CH = HCt / 64;
    const int Gs = 64 / Ht;  // lanes per head
    float s = 0.f, d = 0.f;
    if constexpr (CH == 8) {
        const uint4* hr = (const uint4*)(h + (size_t)wid * HCt) + lane;
        uint4 hv = *hr;
        unsigned wds[4] = {hv.x, hv.y, hv.z, hv.w};
        const f32x4* as4 = (const f32x4*)(asrc + lane * 8);
        const f32x4* ad4 = (const f32x4*)(adst + lane * 8);
        f32x4 av0 = as4[0], av1 = as4[1], dv0 = ad4[0], dv1 = ad4[1];
#pragma unroll
        for (int wv = 0; wv < 4; ++wv) {
            float a0 = (wv < 2) ? av0[2 * wv] : av1[2 * (wv - 2)];
            float a1 = (wv < 2) ? av0[2 * wv + 1] : av1[2 * (wv - 2) + 1];
            float d0 = (wv < 2) ? dv0[2 * wv] : dv1[2 * (wv - 2)];
            float d1 = (wv < 2) ? dv0[2 * wv + 1] : dv1[2 * (wv - 2) + 1];
            fma_mix_lo(s, a0, wds[wv]); fma_mix_hi(s, a1, wds[wv]);
            fma_mix_lo(d, d0, wds[wv]); fma_mix_hi(d, d1, wds[wv]);
        }
    } else {
        // CH == 1 (layer 3): one fp16 per lane
        float hv = h2f_bits(h[(size_t)wid * HCt + lane]);
        s = hv * asrc[lane];
        d = hv * adst[lane];
    }
#pragma unroll
    for (int dd = 1; dd < Gs; dd <<= 1) {
        s += __shfl_xor(s, dd);
        d += __shfl_xor(d, dd);
    }
    if ((lane & (Gs - 1)) == 0) {
        int hh = lane / Gs;
        als[wid * Ht + hh] = s;
        ald[wid * Ht + hh] = d;
    }
}

// ---------------- aggr HC=512 H=4: wave = node, all heads, inline alpha ---
// 64 lanes x 16B = full 1KB h row per edge (fully coalesced gather); lane
// owns channels lane*8..lane*8+7 exclusively -> NO cross-lane reduce at all.
// Per 64-edge chunk: pre-pass where lane e computes edge e's 4 head-alphas
// ONCE (coalesced csr load + one als dwordx4 gather + 4 exps; ald[n] is
// wave-uniform), staged in LDS; quad loop reads its head's 4 alphas with one
// ds_read_b128. Replaces the k_alpha4 dispatch + alpha/dstarr round-trips.
// den per head accumulates redundantly in that head's 16 lanes (free).
// fma_mix keeps the fp16 h multiply at 1 VALU op/channel (R4).
template <bool DOELU>
__global__ __launch_bounds__(256) void k_aggr4d(
    const unsigned short* __restrict__ h, const float* __restrict__ als,
    const float* __restrict__ ald,
    const int* __restrict__ off, const int* __restrict__ csr,
    const float* __restrict__ bias,
    unsigned short* __restrict__ outp, int N)
{
    __shared__ float alpS[4][4][64];   // [wave][head][edge-in-chunk], 4 KiB
    int wid = threadIdx.x >> 6;
    int n = blockIdx.x * 4 + wid;
    if (n >= N) return;
    int lane = threadIdx.x & 63;
    int g4 = lane >> 4;               // this lane's head

    int off0 = off[n], off1 = off[n + 1];
    int degp = off1 - off0;           // multiple of 4 (padded)
    const int4* csr4 = (const int4*)(csr + off0);
    f32x4 ald4 = *(const f32x4*)(ald + (size_t)n * 4);

    float acc[8] = {};
    float den = 0.f;
    const char* hB = (const char*)h;
    const unsigned offp = (unsigned)(lane * 16);   // byte slice within 1KB row

    for (int base = 0; base < degp; base += 64) {
        // ---- pre-pass: one alpha set per edge, computed once ----
        f32x4 av = {0.f, 0.f, 0.f, 0.f};
        int e = base + lane;
        if (e < degp) {
            int s = csr[off0 + e];
            if (s >= 0) {
                f32x4 a4 = *(const f32x4*)(als + (size_t)(unsigned)s * 4);
#pragma unroll
                for (int hh = 0; hh < 4; ++hh) {
                    float l = a4[hh] + ald4[hh];
                    l = l > 0.f ? l : 0.2f * l;
                    av[hh] = __expf(l);
                }
            }
        }
#pragma unroll
        for (int hh = 0; hh < 4; ++hh) alpS[wid][hh][lane] = av[hh];
        // single-wave LDS producer/consumer: compiler inserts lgkmcnt

        // ---- quad loop over this chunk ----
        int qn = (degp - base) >> 2; if (qn > 16) qn = 16;
        int qb = base >> 2;
        for (int qq = 0; qq < qn; ++qq) {
            int4 cs = csr4[qb + qq];
            f32x4 af = *(const f32x4*)&alpS[wid][g4][qq * 4];
            int c0 = cs.x < 0 ? 0 : cs.x;   // pads: alpha=0, clamp address
            int c1 = cs.y < 0 ? 0 : cs.y;
            int c2 = cs.z < 0 ? 0 : cs.z;
            int c3 = cs.w < 0 ? 0 : cs.w;
            uint4 h0 = *(const uint4*)(hB + (size_t)((((unsigned)c0) << 10) + offp));
            uint4 h1 = *(const uint4*)(hB + (size_t)((((unsigned)c1) << 10) + offp));
            uint4 h2 = *(const uint4*)(hB + (size_t)((((unsigned)c2) << 10) + offp));
            uint4 h3 = *(const uint4*)(hB + (size_t)((((unsigned)c3) << 10) + offp));
            den += (af[0] + af[1]) + (af[2] + af[3]);
            unsigned w0[4] = {h0.x, h0.y, h0.z, h0.w};
            unsigned w1[4] = {h1.x, h1.y, h1.z, h1.w};
            unsigned w2[4] = {h2.x, h2.y, h2.z, h2.w};
            unsigned w3[4] = {h3.x, h3.y, h3.z, h3.w};
#pragma unroll
            for (int wv = 0; wv < 4; ++wv) {
                fma_mix_lo(acc[2 * wv],     af[0], w0[wv]);
                fma_mix_hi(acc[2 * wv + 1], af[0], w0[wv]);
            }
#pragma unroll
            for (int wv = 0; wv < 4; ++wv) {
                fma_mix_lo(acc[2 * wv],     af[1], w1[wv]);
                fma_mix_hi(acc[2 * wv + 1], af[1], w1[wv]);
            }
#pragma unroll
            for (int wv = 0; wv < 4; ++wv) {
                fma_mix_lo(acc[2 * wv],     af[2], w2[wv]);
                fma_mix_hi(acc[2 * wv + 1], af[2], w2[wv]);
            }
#pragma unroll
            for (int wv = 0; wv < 4; ++wv) {
                fma_mix_lo(acc[2 * wv],     af[3], w3[wv]);
                fma_mix_hi(acc[2 * wv + 1], af[3], w3[wv]);
            }
        }
    }

    // ---- epilogue: lane-exclusive channels, no reduce ----
    float inv = 1.f / den;
    int cb = lane * 8;
    const f32x4* b4 = (const f32x4*)(bias + cb);
    f32x4 bv0 = b4[0], bv1 = b4[1];
    unsigned ww[4];
#pragma unroll
    for (int wv = 0; wv < 4; ++wv) {
        float v0 = acc[2 * wv] * inv + (wv < 2 ? bv0[2 * wv] : bv1[2 * (wv - 2)]);
        float v1 = acc[2 * wv + 1] * inv + (wv < 2 ? bv0[2 * wv + 1] : bv1[2 * (wv - 2) + 1]);
        if (DOELU) {
            v0 = v0 > 0.f ? v0 : expm1f(v0);
            v1 = v1 > 0.f ? v1 : expm1f(v1);
        }
        ww[wv] = (unsigned)f2h_bits(v0) | ((unsigned)f2h_bits(v1) << 16);
    }
    uint4 o; o.x = ww[0]; o.y = ww[1]; o.z = ww[2]; o.w = ww[3];
    *((uint4*)(outp + (size_t)n * 512 + cb)) = o;   // full 1KB row, coalesced
}

// ---------------- layer-3 aggr (HC=64, H=1, fp16 h), quad-edge, inline exp
__global__ __launch_bounds__(256) void k_aggr1b(
    const unsigned short* __restrict__ h, const float* __restrict__ als,
    const float* __restrict__ aldv, const int* __restrict__ off,
    const int* __restrict__ csr, const float* __restrict__ bias,
    float* __restrict__ outp, int N)
{
    int n = blockIdx.x * (blockDim.x >> 6) + (threadIdx.x >> 6);
    if (n >= N) return;
    int lane = threadIdx.x & 63;
    int g = lane >> 4;
    int p = lane & 15;
    int q0 = (off[n] >> 2) + g, q1 = off[n + 1] >> 2;
    float aldh = aldv[n];

    float acc[4] = {};
    float den = 0.f;
    const char* hB = (const char*)h;
    const unsigned offp = (unsigned)(p * 8);   // bytes; lane owns 4 fp16 (8B)
    const int4* csr4 = (const int4*)csr;

    auto aof = [&](int ss) -> float {
        int sc = ss < 0 ? 0 : ss;
        float l = als[sc] + aldh;
        l = l > 0.f ? l : 0.2f * l;
        float e = __expf(l);
        return ss < 0 ? 0.f : e;
    };
    auto fmaq = [&](float a, const uint2& hq) {
        den += a;
        fma_mix_lo(acc[0], a, hq.x);
        fma_mix_hi(acc[1], a, hq.x);
        fma_mix_lo(acc[2], a, hq.y);
        fma_mix_hi(acc[3], a, hq.y);
    };

    for (int q = q0; q < q1; q += 4) {
        int4 cs = csr4[q];
        float a0 = aof(cs.x), a1 = aof(cs.y), a2 = aof(cs.z), a3 = aof(cs.w);
        uint2 h0 = *(const uint2*)(hB + (size_t)((((unsigned)(cs.x < 0 ? 0 : cs.x)) << 7) + offp));
        uint2 h1 = *(const uint2*)(hB + (size_t)((((unsigned)(cs.y < 0 ? 0 : cs.y)) << 7) + offp));
        uint2 h2 = *(const uint2*)(hB + (size_t)((((unsigned)(cs.z < 0 ? 0 : cs.z)) << 7) + offp));
        uint2 h3 = *(const uint2*)(hB + (size_t)((((unsigned)(cs.w < 0 ? 0 : cs.w)) << 7) + offp));
        fmaq(a0, h0);
        fmaq(a1, h1);
        fmaq(a2, h2);
        fmaq(a3, h3);
    }

    den += __shfl_xor(den, 16);
    den += __shfl_xor(den, 32);
#pragma unroll
    for (int j = 0; j < 4; ++j) {
        acc[j] += __shfl_xor(acc[j], 16);
        acc[j] += __shfl_xor(acc[j], 32);
    }
    if (g == 0) {
        float inv = 1.f / den;
        f32x4 o;
#pragma unroll
        for (int j = 0; j < 4; ++j)
            o[j] = acc[j] * inv + bias[p * 4 + j];
        *((f32x4*)(outp + (size_t)n * 64 + p * 4)) = o;
    }
}

// --------------------------------------------------------------------------
extern "C" void kernel_launch(void* const* d_in, const int* in_sizes, int n_in,
                              void* d_out, int out_size, void* d_ws, size_t ws_size,
                              hipStream_t stream)
{
    const float* x   = (const float*)d_in[0];
    const int*   ei  = (const int*)d_in[1];
    const float* W1  = (const float*)d_in[2];
    const float* as1 = (const float*)d_in[3];
    const float* ad1 = (const float*)d_in[4];
    const float* b1  = (const float*)d_in[5];
    const float* W2  = (const float*)d_in[6];
    const float* as2 = (const float*)d_in[7];
    const float* ad2 = (const float*)d_in[8];
    const float* b2  = (const float*)d_in[9];
    const float* W3  = (const float*)d_in[10];
    const float* as3 = (const float*)d_in[11];
    const float* ad3 = (const float*)d_in[12];
    const float* b3  = (const float*)d_in[13];

    const int DIN = 256, HC = 512, DOUT = 64;
    int N = in_sizes[0] / DIN;
    int E = in_sizes[1] / 2;
    int Mcap = E + 4 * N;  // capacity for 4-padded CSR

    // workspace carve-up
    char* w = (char*)d_ws;
    auto alloc = [&](size_t bytes) -> char* {
        char* p = w;
        w += (bytes + 255) & ~(size_t)255;
        return p;
    };
    int* deg    = (int*)alloc((size_t)N * 4);
    int* cur    = (int*)alloc((size_t)N * 4);
    int* off    = (int*)alloc((size_t)(N + 1) * 4);
    int* csr    = (int*)alloc((size_t)Mcap * 4);
    unsigned short* W1T = (unsigned short*)alloc((size_t)HC * DIN * 2);
    unsigned short* W2T = (unsigned short*)alloc((size_t)HC * HC * 2);
    unsigned short* W3T = (unsigned short*)alloc((size_t)DOUT * HC * 2);
    unsigned short* xb  = (unsigned short*)alloc((size_t)N * DIN * 2);
    unsigned short* act = (unsigned short*)alloc((size_t)N * HC * 2);
    unsigned short* hb  = (unsigned short*)alloc((size_t)N * HC * 2);
    unsigned short* hb3 = (unsigned short*)alloc((size_t)N * DOUT * 2);  // fp16 h (layer 3)
    float* als   = (float*)alloc((size_t)N * 4 * 4);
    float* ald   = (float*)alloc((size_t)N * 4 * 4);

    // ---- build: memset(deg) -> prep(+csr init+hist) -> scan -> fill ----
    hipMemsetAsync(deg, 0, (size_t)N * 4, stream);
    int prep_total = DIN * HC + HC * HC + HC * DOUT + N * DIN + Mcap + E;
    k_prep<<<(prep_total + 255) / 256, 256, 0, stream>>>(
        W1, W1T, W2, W2T, W3, W3T, x, xb, csr, Mcap, ei, E, deg, DIN, HC, DOUT, N);
    k_scan<<<1, 1024, 0, stream>>>(deg, off, cur, N);
    k_fill<<<(E + N + 255) / 256, 256, 0, stream>>>(ei, E, N, cur, csr);

    int tiles_m = (N + 63) / 64;
    auto gemm_blocks = [&](int tn) { return (tiles_m * tn + 3) / 4; };
    int tm128 = (N + 127) / 128;
    int nwave_blocks = (N + 3) / 4;
    int nodeBlocks = (N + 3) / 4;

    // ---- layer 1 ----
    k_gemm_lds<<<tm128 * (HC / 64), 256, 0, stream>>>(xb, W1T, hb, N, DIN, HC, HC / 64);
    k_al<512, 4><<<nwave_blocks, 256, 0, stream>>>(hb, as1, ad1, als, ald, N);
    k_aggr4d<true><<<nodeBlocks, 256, 0, stream>>>(hb, als, ald, off, csr, b1, act, N);

    // ---- layer 2 ----
    k_gemm_lds<<<tm128 * (HC / 64), 256, 0, stream>>>(act, W2T, hb, N, HC, HC, HC / 64);
    k_al<512, 4><<<nwave_blocks, 256, 0, stream>>>(hb, as2, ad2, als, ald, N);
    k_aggr4d<true><<<nodeBlocks, 256, 0, stream>>>(hb, als, ald, off, csr, b2, act, N);

    // ---- layer 3 (fp16 h path; Nc=64, al fused into GEMM epilogue) ----
    k_gemm<true, true><<<gemm_blocks(1), 256, 0, stream>>>(
        act, W3T, hb3, N, HC, DOUT, 1, as3, ad3, als, ald);
    k_aggr1b<<<nwave_blocks, 256, 0, stream>>>(hb3, als, ald, off, csr, b3, (float*)d_out, N);
}

// Round 6
// 283.371 us; speedup vs baseline: 1.0643x; 1.0017x over previous
//
#include <hip/hip_runtime.h>
#include <hip/hip_fp16.h>

typedef _Float16 f16x8 __attribute__((ext_vector_type(8)));
typedef float f32x4 __attribute__((ext_vector_type(4)));

__device__ __forceinline__ unsigned short f2h_bits(float f) {
    __half h = __float2half(f);
    return *reinterpret_cast<unsigned short*>(&h);
}
__device__ __forceinline__ float h2f_bits(unsigned short u) {
    __half h = *reinterpret_cast<__half*>(&u);
    return __half2float(h);
}

// acc += a(f32) * f16_lo(hw)  -- one VOP3P v_fma_mix_f32
__device__ __forceinline__ void fma_mix_lo(float& acc, float a, unsigned hw) {
    asm("v_fma_mix_f32 %0, %1, %2, %0 op_sel_hi:[0,1,0]"
        : "+v"(acc) : "v"(a), "v"(hw));
}
// acc += a(f32) * f16_hi(hw)
__device__ __forceinline__ void fma_mix_hi(float& acc, float a, unsigned hw) {
    asm("v_fma_mix_f32 %0, %1, %2, %0 op_sel:[0,1,0] op_sel_hi:[0,1,0]"
        : "+v"(acc) : "v"(a), "v"(hw));
}

// async 16B global->LDS (DMA path, no VGPR round-trip). LDS dest is
// wave-uniform base + lane*16 (HW rule) -- layout below is linear in lane order.
__device__ __forceinline__ void gload_lds16(const void* g, void* l) {
    __builtin_amdgcn_global_load_lds(
        (const __attribute__((address_space(1))) unsigned int*)g,
        (__attribute__((address_space(3))) unsigned int*)l, 16, 0, 0);
}

// ---------------- prep: W transposes (fp16), x cvt, csr=-1 init, deg hist ----
// deg is zeroed by a preceding hipMemsetAsync (stream-ordered).
__global__ void k_prep(const float* __restrict__ W1, unsigned short* __restrict__ W1T,
                       const float* __restrict__ W2, unsigned short* __restrict__ W2T,
                       const float* __restrict__ W3, unsigned short* __restrict__ W3T,
                       const float* __restrict__ x, unsigned short* __restrict__ xb,
                       int* __restrict__ csr, int Mcap,
                       const int* __restrict__ ei, int E, int* __restrict__ deg,
                       int DIN, int HC, int DOUT, int N)
{
    int i = blockIdx.x * blockDim.x + threadIdx.x;
    int n1 = DIN * HC;
    int n2 = n1 + HC * HC;
    int n3 = n2 + HC * DOUT;
    int n4 = n3 + N * DIN;
    int n5 = n4 + Mcap;
    int n6 = n5 + E;
    if (i < n1) {
        int k = i / HC, n = i - k * HC;
        W1T[n * DIN + k] = f2h_bits(W1[i]);
    } else if (i < n2) {
        int j = i - n1;
        int k = j / HC, n = j - k * HC;
        W2T[n * HC + k] = f2h_bits(W2[j]);
    } else if (i < n3) {
        int j = i - n2;
        int k = j / DOUT, n = j - k * DOUT;
        W3T[n * HC + k] = f2h_bits(W3[j]);
    } else if (i < n4) {
        int j = i - n3;
        xb[j] = f2h_bits(x[j]);
    } else if (i < n5) {
        csr[i - n4] = -1;           // pad sentinel
    } else if (i < n6) {
        atomicAdd(&deg[ei[E + (i - n5)]], 1);
    }
}

// scan of (deg+1) rounded up to multiple of 4 (padded segments)
__global__ void k_scan(const int* __restrict__ deg, int* __restrict__ off,
                       int* __restrict__ cur, int N) {
    __shared__ int sums[1024];
    int t = threadIdx.x;
    int chunk = (N + 1023) >> 10;
    int lo = t * chunk;
    int hi = lo + chunk; if (hi > N) hi = N;
    if (lo > N) lo = N;
    int s = 0;
    for (int i = lo; i < hi; ++i) s += (deg[i] + 4) & ~3;
    sums[t] = s;
    __syncthreads();
    for (int dd = 1; dd < 1024; dd <<= 1) {
        int v = (t >= dd) ? sums[t - dd] : 0;
        __syncthreads();
        sums[t] += v;
        __syncthreads();
    }
    int run = sums[t] - s;  // exclusive prefix
    for (int i = lo; i < hi; ++i) { off[i] = run; cur[i] = run; run += (deg[i] + 4) & ~3; }
    if (t == 1023) off[N] = run;
}
__global__ void k_fill(const int* __restrict__ ei, int E, int N,
                       int* cur, int* __restrict__ csr) {
    int i = blockIdx.x * blockDim.x + threadIdx.x;
    if (i < E) {
        int s = ei[i], d = ei[E + i];
        int pos = atomicAdd(&cur[d], 1);
        csr[pos] = s;
    } else if (i < E + N) {
        int nn = i - E;
        int pos = atomicAdd(&cur[nn], 1);
        csr[pos] = nn;
    }
}

// ---------------- GEMM (layer 3 / small-Nc path): register-only 64x64, fp16 --
// DOAL: fused attention-logit epilogue (valid only when tiles_n==1, i.e. the
// wave's 64 cols are ALL output cols; layer 3, H=1). Per row:
// al_s[row] = sum_col acc*a_src -> 4 FMA + shfl_xor reduce over the 16 r-lanes.
template <bool OUTH, bool DOAL>
__global__ __launch_bounds__(256) void k_gemm(
    const unsigned short* __restrict__ A, const unsigned short* __restrict__ BT,
    void* __restrict__ D, int M, int K, int Nc, int tiles_n,
    const float* __restrict__ asrc, const float* __restrict__ adst,
    float* __restrict__ als, float* __restrict__ ald)
{
    int wid = blockIdx.x * (blockDim.x >> 6) + (threadIdx.x >> 6);
    int tiles_m = (M + 63) >> 6;
    if (wid >= tiles_m * tiles_n) return;
    int lane = threadIdx.x & 63;
    int tm = wid / tiles_n, tn = wid - tm * tiles_n;
    int m0 = tm << 6, n0 = tn << 6;
    int r = lane & 15, q = lane >> 4;

    const unsigned short* Arow[4];
    const unsigned short* Brow[4];
#pragma unroll
    for (int i = 0; i < 4; ++i) {
        int row = m0 + 16 * i + r; row = row < M ? row : M - 1;
        Arow[i] = A + (size_t)row * K + q * 8;
        Brow[i] = BT + (size_t)(n0 + 16 * i + r) * K + q * 8;
    }

    f32x4 acc[4][4] = {};
    f16x8 a[4], b[4], a2[4], b2[4];
#pragma unroll
    for (int i = 0; i < 4; ++i) {
        a[i] = *(const f16x8*)(Arow[i]);
        b[i] = *(const f16x8*)(Brow[i]);
    }
    for (int k0 = 0; k0 < K; k0 += 32) {
        int kn = k0 + 32;
        if (kn < K) {
#pragma unroll
            for (int i = 0; i < 4; ++i) {
                a2[i] = *(const f16x8*)(Arow[i] + kn);
                b2[i] = *(const f16x8*)(Brow[i] + kn);
            }
        }
#pragma unroll
        for (int i = 0; i < 4; ++i)
#pragma unroll
            for (int j = 0; j < 4; ++j)
                acc[i][j] = __builtin_amdgcn_mfma_f32_16x16x32_f16(a[i], b[j], acc[i][j], 0, 0, 0);
        if (kn < K) {
#pragma unroll
            for (int i = 0; i < 4; ++i) { a[i] = a2[i]; b[i] = b2[i]; }
        }
    }
#pragma unroll
    for (int i = 0; i < 4; ++i) {
        int rowb = m0 + 16 * i + q * 4;
#pragma unroll
        for (int rr = 0; rr < 4; ++rr) {
            int row = rowb + rr;
            if (row < M) {
#pragma unroll
                for (int j = 0; j < 4; ++j) {
                    int col = n0 + 16 * j + r;
                    if (OUTH)
                        ((unsigned short*)D)[(size_t)row * Nc + col] = f2h_bits(acc[i][j][rr]);
                    else
                        ((float*)D)[(size_t)row * Nc + col] = acc[i][j][rr];
                }
            }
        }
    }
    if (DOAL) {
        float asl[4], adl[4];
#pragma unroll
        for (int j = 0; j < 4; ++j) { asl[j] = asrc[16 * j + r]; adl[j] = adst[16 * j + r]; }
#pragma unroll
        for (int i = 0; i < 4; ++i) {
#pragma unroll
            for (int rr = 0; rr < 4; ++rr) {
                float s = 0.f, d = 0.f;
#pragma unroll
                for (int j = 0; j < 4; ++j) {
                    s += acc[i][j][rr] * asl[j];
                    d += acc[i][j][rr] * adl[j];
                }
#pragma unroll
                for (int dd = 1; dd < 16; dd <<= 1) {
                    s += __shfl_xor(s, dd);
                    d += __shfl_xor(d, dd);
                }
                int row = m0 + 16 * i + q * 4 + rr;
                if (r == 0 && row < M) { als[row] = s; ald[row] = d; }
            }
        }
    }
}

// ---------------- GEMM (layers 1&2): m97-style 128x64 tile, LDS-staged, fp16 --
// 4 waves (2x2), wave tile 64x32, BK=32. Staging via global_load_lds width 16:
// per K-step each wave DMAs 3 KiB (2 A chunks + 1 B chunk, 1 KiB each, linear
// lane order), 2 barriers per K-step (the measured-874TF m97 schedule).
// BN=64 keeps the grid at (M/128)*(Nc/64)=632 blocks (~2.5/CU) -- at M=10000
// grid occupancy, not per-wave ILP, is the binding constraint.
__global__ __launch_bounds__(256) void k_gemm_lds(
    const unsigned short* __restrict__ A, const unsigned short* __restrict__ BT,
    unsigned short* __restrict__ D, int M, int K, int Nc, int tiles_n)
{
    __shared__ unsigned short As[128 * 32];   // 8 KiB
    __shared__ unsigned short Bs[64 * 32];    // 4 KiB
    int tm = blockIdx.x / tiles_n, tn = blockIdx.x - tm * tiles_n;
    int m0 = tm << 7, n0 = tn << 6;
    int tid = threadIdx.x;
    int w = tid >> 6, lane = tid & 63;
    int wr = w >> 1, wc = w & 1;
    int r = lane & 15, q = lane >> 4;

    // staging: chunk c = 16 tile-rows; lane l -> row c*16 + l/4, bytes (l&3)*16
    int lrow = lane >> 2;
    int lch = (lane & 3) * 8;                  // in fp16 elements
    int ga0 = m0 + w * 16 + lrow;       if (ga0 >= M) ga0 = M - 1;
    int ga1 = m0 + (w + 4) * 16 + lrow; if (ga1 >= M) ga1 = M - 1;
    const unsigned short* pa0 = A + (size_t)ga0 * K + lch;
    const unsigned short* pa1 = A + (size_t)ga1 * K + lch;
    const unsigned short* pb  = BT + (size_t)(n0 + w * 16 + lrow) * K + lch;
    unsigned short* lA0 = As + w * 512;        // wave-uniform LDS chunk bases
    unsigned short* lA1 = As + (w + 4) * 512;
    unsigned short* lB  = Bs + w * 512;

    const unsigned short* arp = As + (wr * 64 + r) * 32 + q * 8;
    const unsigned short* brp = Bs + (wc * 32 + r) * 32 + q * 8;

    f32x4 acc[4][2] = {};
    for (int k0 = 0; k0 < K; k0 += 32) {
        gload_lds16(pa0 + k0, lA0);
        gload_lds16(pa1 + k0, lA1);
        gload_lds16(pb + k0, lB);
        __syncthreads();                        // compiler drains vmcnt(0) here
        f16x8 a[4], b[2];
#pragma unroll
        for (int i = 0; i < 4; ++i) a[i] = *(const f16x8*)(arp + i * 16 * 32);
#pragma unroll
        for (int j = 0; j < 2; ++j) b[j] = *(const f16x8*)(brp + j * 16 * 32);
#pragma unroll
        for (int i = 0; i < 4; ++i)
#pragma unroll
            for (int j = 0; j < 2; ++j)
                acc[i][j] = __builtin_amdgcn_mfma_f32_16x16x32_f16(a[i], b[j], acc[i][j], 0, 0, 0);
        __syncthreads();                        // protect LDS before next stage
    }
#pragma unroll
    for (int i = 0; i < 4; ++i) {
        int rowb = m0 + wr * 64 + 16 * i + q * 4;
#pragma unroll
        for (int rr = 0; rr < 4; ++rr) {
            int row = rowb + rr;
            if (row < M) {
#pragma unroll
                for (int j = 0; j < 2; ++j) {
                    int col = n0 + wc * 32 + 16 * j + r;
                    D[(size_t)row * Nc + col] = f2h_bits(acc[i][j][rr]);
                }
            }
        }
    }
}

// ---------------- attention logits per node: al_s, al_d (fp16 h) ----------
template <int HCt, int Ht>
__global__ __launch_bounds__(256) void k_al(
    const unsigned short* __restrict__ h, const float* __restrict__ asrc,
    const float* __restrict__ adst,
    float* __restrict__ als, float* __restrict__ ald, int N)
{
    int wid = blockIdx.x * (blockDim.x >> 6) + (threadIdx.x >> 6);
    if (wid >= N) return;
    int lane = threadIdx.x & 63;
    const int CH = HCt / 64;
    const int Gs = 64 / Ht;  // lanes per head
    float s = 0.f, d = 0.f;
    if constexpr (CH == 8) {
        const uint4* hr = (const uint4*)(h + (size_t)wid * HCt) + lane;
        uint4 hv = *hr;
        unsigned wds[4] = {hv.x, hv.y, hv.z, hv.w};
        const f32x4* as4 = (const f32x4*)(asrc + lane * 8);
        const f32x4* ad4 = (const f32x4*)(adst + lane * 8);
        f32x4 av0 = as4[0], av1 = as4[1], dv0 = ad4[0], dv1 = ad4[1];
#pragma unroll
        for (int wv = 0; wv < 4; ++wv) {
            float a0 = (wv < 2) ? av0[2 * wv] : av1[2 * (wv - 2)];
            float a1 = (wv < 2) ? av0[2 * wv + 1] : av1[2 * (wv - 2) + 1];
            float d0 = (wv < 2) ? dv0[2 * wv] : dv1[2 * (wv - 2)];
            float d1 = (wv < 2) ? dv0[2 * wv + 1] : dv1[2 * (wv - 2) + 1];
            fma_mix_lo(s, a0, wds[wv]); fma_mix_hi(s, a1, wds[wv]);
            fma_mix_lo(d, d0, wds[wv]); fma_mix_hi(d, d1, wds[wv]);
        }
    } else {
        // CH == 1 (layer 3): one fp16 per lane
        float hv = h2f_bits(h[(size_t)wid * HCt + lane]);
        s = hv * asrc[lane];
        d = hv * adst[lane];
    }
#pragma unroll
    for (int dd = 1; dd < Gs; dd <<= 1) {
        s += __shfl_xor(s, dd);
        d += __shfl_xor(d, dd);
    }
    if ((lane & (Gs - 1)) == 0) {
        int hh = lane / Gs;
        als[wid * Ht + hh] = s;
        ald[wid * Ht + hh] = d;
    }
}

// ---------------- aggr HC=512 H=4: (node,head) slab + chunk-prepass alpha --
// Wave = (node, head); head-major grid keeps each XCD's h-gather window to a
// 2.56MB head plane (L2-resident; R2 counters: 86% L2 hit. R5's all-head rows
// spread to 10MB/L3 and gave the ~10us back). Per 64-edge chunk: PREPASS --
// lane e computes alpha(e, head) ONCE (coalesced csr load, 4B als gather,
// wave-uniform ald, 1 exp) -> 256B LDS; QUAD loop -- 4 groups x 16 lanes, 4
// edges/group/iter: int4 csr + ds_read_b128 alphas + 4x uint4 h (256B head
// slice, saddr-form) + 32 fma_mix. Replaces k_alpha4 dispatch + 11.5MB
// round-trip with in-loop exp hidden under gather latency (1 exp/edge, no
// R2-style 16x redundancy). Pads: alpha=0, address clamped.
template <bool DOELU>
__global__ __launch_bounds__(256) void k_aggr4e(
    const unsigned short* __restrict__ h, const float* __restrict__ als,
    const float* __restrict__ ald,
    const int* __restrict__ off, const int* __restrict__ csr,
    const float* __restrict__ bias,
    unsigned short* __restrict__ outp, int N, int nodeBlocks)
{
    __shared__ float alpS[4][64];     // [wave][edge-in-chunk], 1 KiB
    int head = blockIdx.x / nodeBlocks;
    int nb = blockIdx.x - head * nodeBlocks;
    int wid = threadIdx.x >> 6;
    int n = nb * 4 + wid;
    if (n >= N) return;
    int lane = threadIdx.x & 63;
    int g = lane >> 4;                // edge group 0..3
    int p = lane & 15;                // channel-lane within group

    int off0 = off[n];
    int degp = off[n + 1] - off0;     // multiple of 4 (padded)
    float aldh = ald[n * 4 + head];
    const char* hB = (const char*)h;
    const unsigned offp = (unsigned)(head * 256 + p * 16);   // bytes within row
    const int4* csr4 = (const int4*)(csr + off0);

    float acc[8] = {};
    float den = 0.f;

    for (int base = 0; base < degp; base += 64) {
        // ---- prepass: one alpha per edge at this head ----
        float av = 0.f;
        int e = base + lane;
        if (e < degp) {
            int s = csr[off0 + e];
            if (s >= 0) {
                float l = als[(size_t)(unsigned)s * 4 + head] + aldh;
                l = l > 0.f ? l : 0.2f * l;
                av = __expf(l);
            }
        }
        alpS[wid][lane] = av;
        // single-wave LDS producer->consumer: DS pipe is in-order per wave

        // ---- quad loop: groups split the (up to) 16 quads of this chunk ----
        int qn = (degp - base) >> 2; if (qn > 16) qn = 16;
        int qb = base >> 2;
        for (int qq = g; qq < qn; qq += 4) {
            int4 cs = csr4[qb + qq];
            f32x4 af = *(const f32x4*)&alpS[wid][qq * 4];
            int c0 = cs.x < 0 ? 0 : cs.x;   // pads: alpha=0, clamp address
            int c1 = cs.y < 0 ? 0 : cs.y;
            int c2 = cs.z < 0 ? 0 : cs.z;
            int c3 = cs.w < 0 ? 0 : cs.w;
            uint4 h0 = *(const uint4*)(hB + (size_t)((((unsigned)c0) << 10) + offp));
            uint4 h1 = *(const uint4*)(hB + (size_t)((((unsigned)c1) << 10) + offp));
            uint4 h2 = *(const uint4*)(hB + (size_t)((((unsigned)c2) << 10) + offp));
            uint4 h3 = *(const uint4*)(hB + (size_t)((((unsigned)c3) << 10) + offp));
            den += (af[0] + af[1]) + (af[2] + af[3]);
            unsigned w0[4] = {h0.x, h0.y, h0.z, h0.w};
            unsigned w1[4] = {h1.x, h1.y, h1.z, h1.w};
            unsigned w2[4] = {h2.x, h2.y, h2.z, h2.w};
            unsigned w3[4] = {h3.x, h3.y, h3.z, h3.w};
#pragma unroll
            for (int wv = 0; wv < 4; ++wv) {
                fma_mix_lo(acc[2 * wv],     af[0], w0[wv]);
                fma_mix_hi(acc[2 * wv + 1], af[0], w0[wv]);
            }
#pragma unroll
            for (int wv = 0; wv < 4; ++wv) {
                fma_mix_lo(acc[2 * wv],     af[1], w1[wv]);
                fma_mix_hi(acc[2 * wv + 1], af[1], w1[wv]);
            }
#pragma unroll
            for (int wv = 0; wv < 4; ++wv) {
                fma_mix_lo(acc[2 * wv],     af[2], w2[wv]);
                fma_mix_hi(acc[2 * wv + 1], af[2], w2[wv]);
            }
#pragma unroll
            for (int wv = 0; wv < 4; ++wv) {
                fma_mix_lo(acc[2 * wv],     af[3], w3[wv]);
                fma_mix_hi(acc[2 * wv + 1], af[3], w3[wv]);
            }
        }
    }

    den += __shfl_xor(den, 16);
    den += __shfl_xor(den, 32);
#pragma unroll
    for (int j = 0; j < 8; ++j) {
        acc[j] += __shfl_xor(acc[j], 16);
        acc[j] += __shfl_xor(acc[j], 32);
    }

    if (g == 0) {
        float inv = 1.f / den;
        int cb = head * 128 + p * 8;
        unsigned ww[4];
#pragma unroll
        for (int wv = 0; wv < 4; ++wv) {
            float v0 = acc[2 * wv] * inv + bias[cb + 2 * wv];
            float v1 = acc[2 * wv + 1] * inv + bias[cb + 2 * wv + 1];
            if (DOELU) {
                v0 = v0 > 0.f ? v0 : expm1f(v0);
                v1 = v1 > 0.f ? v1 : expm1f(v1);
            }
            ww[wv] = (unsigned)f2h_bits(v0) | ((unsigned)f2h_bits(v1) << 16);
        }
        uint4 o; o.x = ww[0]; o.y = ww[1]; o.z = ww[2]; o.w = ww[3];
        *((uint4*)(outp + (size_t)n * 512 + cb)) = o;
    }
}

// ---------------- layer-3 aggr (HC=64, H=1, fp16 h), quad-edge, inline exp
__global__ __launch_bounds__(256) void k_aggr1b(
    const unsigned short* __restrict__ h, const float* __restrict__ als,
    const float* __restrict__ aldv, const int* __restrict__ off,
    const int* __restrict__ csr, const float* __restrict__ bias,
    float* __restrict__ outp, int N)
{
    int n = blockIdx.x * (blockDim.x >> 6) + (threadIdx.x >> 6);
    if (n >= N) return;
    int lane = threadIdx.x & 63;
    int g = lane >> 4;
    int p = lane & 15;
    int q0 = (off[n] >> 2) + g, q1 = off[n + 1] >> 2;
    float aldh = aldv[n];

    float acc[4] = {};
    float den = 0.f;
    const char* hB = (const char*)h;
    const unsigned offp = (unsigned)(p * 8);   // bytes; lane owns 4 fp16 (8B)
    const int4* csr4 = (const int4*)csr;

    auto aof = [&](int ss) -> float {
        int sc = ss < 0 ? 0 : ss;
        float l = als[sc] + aldh;
        l = l > 0.f ? l : 0.2f * l;
        float e = __expf(l);
        return ss < 0 ? 0.f : e;
    };
    auto fmaq = [&](float a, const uint2& hq) {
        den += a;
        fma_mix_lo(acc[0], a, hq.x);
        fma_mix_hi(acc[1], a, hq.x);
        fma_mix_lo(acc[2], a, hq.y);
        fma_mix_hi(acc[3], a, hq.y);
    };

    for (int q = q0; q < q1; q += 4) {
        int4 cs = csr4[q];
        float a0 = aof(cs.x), a1 = aof(cs.y), a2 = aof(cs.z), a3 = aof(cs.w);
        uint2 h0 = *(const uint2*)(hB + (size_t)((((unsigned)(cs.x < 0 ? 0 : cs.x)) << 7) + offp));
        uint2 h1 = *(const uint2*)(hB + (size_t)((((unsigned)(cs.y < 0 ? 0 : cs.y)) << 7) + offp));
        uint2 h2 = *(const uint2*)(hB + (size_t)((((unsigned)(cs.z < 0 ? 0 : cs.z)) << 7) + offp));
        uint2 h3 = *(const uint2*)(hB + (size_t)((((unsigned)(cs.w < 0 ? 0 : cs.w)) << 7) + offp));
        fmaq(a0, h0);
        fmaq(a1, h1);
        fmaq(a2, h2);
        fmaq(a3, h3);
    }

    den += __shfl_xor(den, 16);
    den += __shfl_xor(den, 32);
#pragma unroll
    for (int j = 0; j < 4; ++j) {
        acc[j] += __shfl_xor(acc[j], 16);
        acc[j] += __shfl_xor(acc[j], 32);
    }
    if (g == 0) {
        float inv = 1.f / den;
        f32x4 o;
#pragma unroll
        for (int j = 0; j < 4; ++j)
            o[j] = acc[j] * inv + bias[p * 4 + j];
        *((f32x4*)(outp + (size_t)n * 64 + p * 4)) = o;
    }
}

// --------------------------------------------------------------------------
extern "C" void kernel_launch(void* const* d_in, const int* in_sizes, int n_in,
                              void* d_out, int out_size, void* d_ws, size_t ws_size,
                              hipStream_t stream)
{
    const float* x   = (const float*)d_in[0];
    const int*   ei  = (const int*)d_in[1];
    const float* W1  = (const float*)d_in[2];
    const float* as1 = (const float*)d_in[3];
    const float* ad1 = (const float*)d_in[4];
    const float* b1  = (const float*)d_in[5];
    const float* W2  = (const float*)d_in[6];
    const float* as2 = (const float*)d_in[7];
    const float* ad2 = (const float*)d_in[8];
    const float* b2  = (const float*)d_in[9];
    const float* W3  = (const float*)d_in[10];
    const float* as3 = (const float*)d_in[11];
    const float* ad3 = (const float*)d_in[12];
    const float* b3  = (const float*)d_in[13];

    const int DIN = 256, HC = 512, DOUT = 64;
    int N = in_sizes[0] / DIN;
    int E = in_sizes[1] / 2;
    int Mcap = E + 4 * N;  // capacity for 4-padded CSR

    // workspace carve-up
    char* w = (char*)d_ws;
    auto alloc = [&](size_t bytes) -> char* {
        char* p = w;
        w += (bytes + 255) & ~(size_t)255;
        return p;
    };
    int* deg    = (int*)alloc((size_t)N * 4);
    int* cur    = (int*)alloc((size_t)N * 4);
    int* off    = (int*)alloc((size_t)(N + 1) * 4);
    int* csr    = (int*)alloc((size_t)Mcap * 4);
    unsigned short* W1T = (unsigned short*)alloc((size_t)HC * DIN * 2);
    unsigned short* W2T = (unsigned short*)alloc((size_t)HC * HC * 2);
    unsigned short* W3T = (unsigned short*)alloc((size_t)DOUT * HC * 2);
    unsigned short* xb  = (unsigned short*)alloc((size_t)N * DIN * 2);
    unsigned short* act = (unsigned short*)alloc((size_t)N * HC * 2);
    unsigned short* hb  = (unsigned short*)alloc((size_t)N * HC * 2);
    unsigned short* hb3 = (unsigned short*)alloc((size_t)N * DOUT * 2);  // fp16 h (layer 3)
    float* als   = (float*)alloc((size_t)N * 4 * 4);
    float* ald   = (float*)alloc((size_t)N * 4 * 4);

    // ---- build: memset(deg) -> prep(+csr init+hist) -> scan -> fill ----
    hipMemsetAsync(deg, 0, (size_t)N * 4, stream);
    int prep_total = DIN * HC + HC * HC + HC * DOUT + N * DIN + Mcap + E;
    k_prep<<<(prep_total + 255) / 256, 256, 0, stream>>>(
        W1, W1T, W2, W2T, W3, W3T, x, xb, csr, Mcap, ei, E, deg, DIN, HC, DOUT, N);
    k_scan<<<1, 1024, 0, stream>>>(deg, off, cur, N);
    k_fill<<<(E + N + 255) / 256, 256, 0, stream>>>(ei, E, N, cur, csr);

    int tiles_m = (N + 63) / 64;
    auto gemm_blocks = [&](int tn) { return (tiles_m * tn + 3) / 4; };
    int tm128 = (N + 127) / 128;
    int nwave_blocks = (N + 3) / 4;
    int nodeBlocks = (N + 3) / 4;

    // ---- layer 1 ----
    k_gemm_lds<<<tm128 * (HC / 64), 256, 0, stream>>>(xb, W1T, hb, N, DIN, HC, HC / 64);
    k_al<512, 4><<<nwave_blocks, 256, 0, stream>>>(hb, as1, ad1, als, ald, N);
    k_aggr4e<true><<<4 * nodeBlocks, 256, 0, stream>>>(hb, als, ald, off, csr, b1, act, N, nodeBlocks);

    // ---- layer 2 ----
    k_gemm_lds<<<tm128 * (HC / 64), 256, 0, stream>>>(act, W2T, hb, N, HC, HC, HC / 64);
    k_al<512, 4><<<nwave_blocks, 256, 0, stream>>>(hb, as2, ad2, als, ald, N);
    k_aggr4e<true><<<4 * nodeBlocks, 256, 0, stream>>>(hb, als, ald, off, csr, b2, act, N, nodeBlocks);

    // ---- layer 3 (fp16 h path; Nc=64, al fused into GEMM epilogue) ----
    k_gemm<true, true><<<gemm_blocks(1), 256, 0, stream>>>(
        act, W3T, hb3, N, HC, DOUT, 1, as3, ad3, als, ald);
    k_aggr1b<<<nwave_blocks, 256, 0, stream>>>(hb3, als, ald, off, csr, b3, (float*)d_out, N);
}

// Round 7
// 263.785 us; speedup vs baseline: 1.1433x; 1.0743x over previous
//
#include <hip/hip_runtime.h>
#include <hip/hip_fp16.h>

typedef _Float16 f16x8 __attribute__((ext_vector_type(8)));
typedef float f32x4 __attribute__((ext_vector_type(4)));

__device__ __forceinline__ unsigned short f2h_bits(float f) {
    __half h = __float2half(f);
    return *reinterpret_cast<unsigned short*>(&h);
}
__device__ __forceinline__ float h2f_bits(unsigned short u) {
    __half h = *reinterpret_cast<__half*>(&u);
    return __half2float(h);
}

// acc += a(f32) * f16_lo(hw)  -- one VOP3P v_fma_mix_f32
__device__ __forceinline__ void fma_mix_lo(float& acc, float a, unsigned hw) {
    asm("v_fma_mix_f32 %0, %1, %2, %0 op_sel_hi:[0,1,0]"
        : "+v"(acc) : "v"(a), "v"(hw));
}
// acc += a(f32) * f16_hi(hw)
__device__ __forceinline__ void fma_mix_hi(float& acc, float a, unsigned hw) {
    asm("v_fma_mix_f32 %0, %1, %2, %0 op_sel:[0,1,0] op_sel_hi:[0,1,0]"
        : "+v"(acc) : "v"(a), "v"(hw));
}

// fast ELU: x>0 ? x : e^x-1  (exp never NaN; select discards the inf branch)
__device__ __forceinline__ float elu_fast(float v) {
    float e = __expf(v) - 1.f;
    return v > 0.f ? v : e;
}

// async 16B global->LDS (DMA path, no VGPR round-trip). LDS dest is
// wave-uniform base + lane*16 (HW rule) -- layout below is linear in lane order.
__device__ __forceinline__ void gload_lds16(const void* g, void* l) {
    __builtin_amdgcn_global_load_lds(
        (const __attribute__((address_space(1))) unsigned int*)g,
        (__attribute__((address_space(3))) unsigned int*)l, 16, 0, 0);
}

// ---------------- prep: W transposes (fp16), x cvt, csr=-1 init, deg hist ----
// deg is zeroed by a preceding hipMemsetAsync (stream-ordered).
__global__ void k_prep(const float* __restrict__ W1, unsigned short* __restrict__ W1T,
                       const float* __restrict__ W2, unsigned short* __restrict__ W2T,
                       const float* __restrict__ W3, unsigned short* __restrict__ W3T,
                       const float* __restrict__ x, unsigned short* __restrict__ xb,
                       int* __restrict__ csr, int Mcap,
                       const int* __restrict__ ei, int E, int* __restrict__ deg,
                       int DIN, int HC, int DOUT, int N)
{
    int i = blockIdx.x * blockDim.x + threadIdx.x;
    int n1 = DIN * HC;
    int n2 = n1 + HC * HC;
    int n3 = n2 + HC * DOUT;
    int n4 = n3 + N * DIN;
    int n5 = n4 + Mcap;
    int n6 = n5 + E;
    if (i < n1) {
        int k = i / HC, n = i - k * HC;
        W1T[n * DIN + k] = f2h_bits(W1[i]);
    } else if (i < n2) {
        int j = i - n1;
        int k = j / HC, n = j - k * HC;
        W2T[n * HC + k] = f2h_bits(W2[j]);
    } else if (i < n3) {
        int j = i - n2;
        int k = j / DOUT, n = j - k * DOUT;
        W3T[n * HC + k] = f2h_bits(W3[j]);
    } else if (i < n4) {
        int j = i - n3;
        xb[j] = f2h_bits(x[j]);
    } else if (i < n5) {
        csr[i - n4] = -1;           // pad sentinel
    } else if (i < n6) {
        atomicAdd(&deg[ei[E + (i - n5)]], 1);
    }
}

// scan of (deg+1) rounded up to multiple of 4 (padded segments)
__global__ void k_scan(const int* __restrict__ deg, int* __restrict__ off,
                       int* __restrict__ cur, int N) {
    __shared__ int sums[1024];
    int t = threadIdx.x;
    int chunk = (N + 1023) >> 10;
    int lo = t * chunk;
    int hi = lo + chunk; if (hi > N) hi = N;
    if (lo > N) lo = N;
    int s = 0;
    for (int i = lo; i < hi; ++i) s += (deg[i] + 4) & ~3;
    sums[t] = s;
    __syncthreads();
    for (int dd = 1; dd < 1024; dd <<= 1) {
        int v = (t >= dd) ? sums[t - dd] : 0;
        __syncthreads();
        sums[t] += v;
        __syncthreads();
    }
    int run = sums[t] - s;  // exclusive prefix
    for (int i = lo; i < hi; ++i) { off[i] = run; cur[i] = run; run += (deg[i] + 4) & ~3; }
    if (t == 1023) off[N] = run;
}
__global__ void k_fill(const int* __restrict__ ei, int E, int N,
                       int* cur, int* __restrict__ csr) {
    int i = blockIdx.x * blockDim.x + threadIdx.x;
    if (i < E) {
        int s = ei[i], d = ei[E + i];
        int pos = atomicAdd(&cur[d], 1);
        csr[pos] = s;
    } else if (i < E + N) {
        int nn = i - E;
        int pos = atomicAdd(&cur[nn], 1);
        csr[pos] = nn;
    }
}

// ---------------- GEMM (layer 3 / small-Nc path): register-only 64x64, fp16 --
// DOAL: fused attention-logit epilogue (valid only when tiles_n==1, i.e. the
// wave's 64 cols are ALL output cols; layer 3, H=1). Per row:
// al_s[row] = sum_col acc*a_src -> 4 FMA + shfl_xor reduce over the 16 r-lanes.
template <bool OUTH, bool DOAL>
__global__ __launch_bounds__(256) void k_gemm(
    const unsigned short* __restrict__ A, const unsigned short* __restrict__ BT,
    void* __restrict__ D, int M, int K, int Nc, int tiles_n,
    const float* __restrict__ asrc, const float* __restrict__ adst,
    float* __restrict__ als, float* __restrict__ ald)
{
    int wid = blockIdx.x * (blockDim.x >> 6) + (threadIdx.x >> 6);
    int tiles_m = (M + 63) >> 6;
    if (wid >= tiles_m * tiles_n) return;
    int lane = threadIdx.x & 63;
    int tm = wid / tiles_n, tn = wid - tm * tiles_n;
    int m0 = tm << 6, n0 = tn << 6;
    int r = lane & 15, q = lane >> 4;

    const unsigned short* Arow[4];
    const unsigned short* Brow[4];
#pragma unroll
    for (int i = 0; i < 4; ++i) {
        int row = m0 + 16 * i + r; row = row < M ? row : M - 1;
        Arow[i] = A + (size_t)row * K + q * 8;
        Brow[i] = BT + (size_t)(n0 + 16 * i + r) * K + q * 8;
    }

    f32x4 acc[4][4] = {};
    f16x8 a[4], b[4], a2[4], b2[4];
#pragma unroll
    for (int i = 0; i < 4; ++i) {
        a[i] = *(const f16x8*)(Arow[i]);
        b[i] = *(const f16x8*)(Brow[i]);
    }
    for (int k0 = 0; k0 < K; k0 += 32) {
        int kn = k0 + 32;
        if (kn < K) {
#pragma unroll
            for (int i = 0; i < 4; ++i) {
                a2[i] = *(const f16x8*)(Arow[i] + kn);
                b2[i] = *(const f16x8*)(Brow[i] + kn);
            }
        }
#pragma unroll
        for (int i = 0; i < 4; ++i)
#pragma unroll
            for (int j = 0; j < 4; ++j)
                acc[i][j] = __builtin_amdgcn_mfma_f32_16x16x32_f16(a[i], b[j], acc[i][j], 0, 0, 0);
        if (kn < K) {
#pragma unroll
            for (int i = 0; i < 4; ++i) { a[i] = a2[i]; b[i] = b2[i]; }
        }
    }
#pragma unroll
    for (int i = 0; i < 4; ++i) {
        int rowb = m0 + 16 * i + q * 4;
#pragma unroll
        for (int rr = 0; rr < 4; ++rr) {
            int row = rowb + rr;
            if (row < M) {
#pragma unroll
                for (int j = 0; j < 4; ++j) {
                    int col = n0 + 16 * j + r;
                    if (OUTH)
                        ((unsigned short*)D)[(size_t)row * Nc + col] = f2h_bits(acc[i][j][rr]);
                    else
                        ((float*)D)[(size_t)row * Nc + col] = acc[i][j][rr];
                }
            }
        }
    }
    if (DOAL) {
        float asl[4], adl[4];
#pragma unroll
        for (int j = 0; j < 4; ++j) { asl[j] = asrc[16 * j + r]; adl[j] = adst[16 * j + r]; }
#pragma unroll
        for (int i = 0; i < 4; ++i) {
#pragma unroll
            for (int rr = 0; rr < 4; ++rr) {
                float s = 0.f, d = 0.f;
#pragma unroll
                for (int j = 0; j < 4; ++j) {
                    s += acc[i][j][rr] * asl[j];
                    d += acc[i][j][rr] * adl[j];
                }
#pragma unroll
                for (int dd = 1; dd < 16; dd <<= 1) {
                    s += __shfl_xor(s, dd);
                    d += __shfl_xor(d, dd);
                }
                int row = m0 + 16 * i + q * 4 + rr;
                if (r == 0 && row < M) { als[row] = s; ald[row] = d; }
            }
        }
    }
}

// ---------------- GEMM (layers 1&2): m97-style 128x64 tile, LDS-staged, fp16 --
// 4 waves (2x2), wave tile 64x32, BK=32. Staging via global_load_lds width 16:
// per K-step each wave DMAs 3 KiB (2 A chunks + 1 B chunk, 1 KiB each, linear
// lane order), 2 barriers per K-step (the measured-874TF m97 schedule).
// BN=64 keeps the grid at (M/128)*(Nc/64)=632 blocks (~2.5/CU) -- at M=10000
// grid occupancy, not per-wave ILP, is the binding constraint.
__global__ __launch_bounds__(256) void k_gemm_lds(
    const unsigned short* __restrict__ A, const unsigned short* __restrict__ BT,
    unsigned short* __restrict__ D, int M, int K, int Nc, int tiles_n)
{
    __shared__ unsigned short As[128 * 32];   // 8 KiB
    __shared__ unsigned short Bs[64 * 32];    // 4 KiB
    int tm = blockIdx.x / tiles_n, tn = blockIdx.x - tm * tiles_n;
    int m0 = tm << 7, n0 = tn << 6;
    int tid = threadIdx.x;
    int w = tid >> 6, lane = tid & 63;
    int wr = w >> 1, wc = w & 1;
    int r = lane & 15, q = lane >> 4;

    // staging: chunk c = 16 tile-rows; lane l -> row c*16 + l/4, bytes (l&3)*16
    int lrow = lane >> 2;
    int lch = (lane & 3) * 8;                  // in fp16 elements
    int ga0 = m0 + w * 16 + lrow;       if (ga0 >= M) ga0 = M - 1;
    int ga1 = m0 + (w + 4) * 16 + lrow; if (ga1 >= M) ga1 = M - 1;
    const unsigned short* pa0 = A + (size_t)ga0 * K + lch;
    const unsigned short* pa1 = A + (size_t)ga1 * K + lch;
    const unsigned short* pb  = BT + (size_t)(n0 + w * 16 + lrow) * K + lch;
    unsigned short* lA0 = As + w * 512;        // wave-uniform LDS chunk bases
    unsigned short* lA1 = As + (w + 4) * 512;
    unsigned short* lB  = Bs + w * 512;

    const unsigned short* arp = As + (wr * 64 + r) * 32 + q * 8;
    const unsigned short* brp = Bs + (wc * 32 + r) * 32 + q * 8;

    f32x4 acc[4][2] = {};
    for (int k0 = 0; k0 < K; k0 += 32) {
        gload_lds16(pa0 + k0, lA0);
        gload_lds16(pa1 + k0, lA1);
        gload_lds16(pb + k0, lB);
        __syncthreads();                        // compiler drains vmcnt(0) here
        f16x8 a[4], b[2];
#pragma unroll
        for (int i = 0; i < 4; ++i) a[i] = *(const f16x8*)(arp + i * 16 * 32);
#pragma unroll
        for (int j = 0; j < 2; ++j) b[j] = *(const f16x8*)(brp + j * 16 * 32);
#pragma unroll
        for (int i = 0; i < 4; ++i)
#pragma unroll
            for (int j = 0; j < 2; ++j)
                acc[i][j] = __builtin_amdgcn_mfma_f32_16x16x32_f16(a[i], b[j], acc[i][j], 0, 0, 0);
        __syncthreads();                        // protect LDS before next stage
    }
#pragma unroll
    for (int i = 0; i < 4; ++i) {
        int rowb = m0 + wr * 64 + 16 * i + q * 4;
#pragma unroll
        for (int rr = 0; rr < 4; ++rr) {
            int row = rowb + rr;
            if (row < M) {
#pragma unroll
                for (int j = 0; j < 2; ++j) {
                    int col = n0 + wc * 32 + 16 * j + r;
                    D[(size_t)row * Nc + col] = f2h_bits(acc[i][j][rr]);
                }
            }
        }
    }
}

// ---------------- attention logits per node: al_s, al_d (fp16 h) ----------
template <int HCt, int Ht>
__global__ __launch_bounds__(256) void k_al(
    const unsigned short* __restrict__ h, const float* __restrict__ asrc,
    const float* __restrict__ adst,
    float* __restrict__ als, float* __restrict__ ald, int N)
{
    int wid = blockIdx.x * (blockDim.x >> 6) + (threadIdx.x >> 6);
    if (wid >= N) return;
    int lane = threadIdx.x & 63;
    const int CH = HCt / 64;
    const int Gs = 64 / Ht;  // lanes per head
    float s = 0.f, d = 0.f;
    if constexpr (CH == 8) {
        const uint4* hr = (const uint4*)(h + (size_t)wid * HCt) + lane;
        uint4 hv = *hr;
        unsigned wds[4] = {hv.x, hv.y, hv.z, hv.w};
        const f32x4* as4 = (const f32x4*)(asrc + lane * 8);
        const f32x4* ad4 = (const f32x4*)(adst + lane * 8);
        f32x4 av0 = as4[0], av1 = as4[1], dv0 = ad4[0], dv1 = ad4[1];
#pragma unroll
        for (int wv = 0; wv < 4; ++wv) {
            float a0 = (wv < 2) ? av0[2 * wv] : av1[2 * (wv - 2)];
            float a1 = (wv < 2) ? av0[2 * wv + 1] : av1[2 * (wv - 2) + 1];
            float d0 = (wv < 2) ? dv0[2 * wv] : dv1[2 * (wv - 2)];
            float d1 = (wv < 2) ? dv0[2 * wv + 1] : dv1[2 * (wv - 2) + 1];
            fma_mix_lo(s, a0, wds[wv]); fma_mix_hi(s, a1, wds[wv]);
            fma_mix_lo(d, d0, wds[wv]); fma_mix_hi(d, d1, wds[wv]);
        }
    } else {
        // CH == 1 (layer 3): one fp16 per lane
        float hv = h2f_bits(h[(size_t)wid * HCt + lane]);
        s = hv * asrc[lane];
        d = hv * adst[lane];
    }
#pragma unroll
    for (int dd = 1; dd < Gs; dd <<= 1) {
        s += __shfl_xor(s, dd);
        d += __shfl_xor(d, dd);
    }
    if ((lane & (Gs - 1)) == 0) {
        int hh = lane / Gs;
        als[wid * Ht + hh] = s;
        ald[wid * Ht + hh] = d;
    }
}

// ---------------- aggr HC=512 H=4: (node,head) slab, prepass, LDS csr ------
// Wave = (node, head); head-major grid keeps each XCD's h-gather window to a
// 2.56MB head plane (L2-resident; R2: 86% L2 hit). Per 64-edge chunk: PREPASS
// computes alpha(e,head) once per edge (coalesced csr load, 4B als gather,
// wave-uniform ald, 1 exp) and stages BOTH alpha and pre-clamped csr in LDS;
// QUAD loop reads int4 csr + f32x4 alpha via broadcast ds_read (no global csr
// reload, no per-iter clamps). R6 counters showed aggr is fixed-overhead
// bound (VALUBusy 63% vs ~7us of useful-work issue): epilogue ELU uses
// exp-1+select (~30 insts) instead of the ~200-inst expm1f expansion.
template <bool DOELU>
__global__ __launch_bounds__(256) void k_aggr4f(
    const unsigned short* __restrict__ h, const float* __restrict__ als,
    const float* __restrict__ ald,
    const int* __restrict__ off, const int* __restrict__ csr,
    const float* __restrict__ bias,
    unsigned short* __restrict__ outp, int N, int nodeBlocks)
{
    __shared__ float alpS[4][64];     // [wave][edge-in-chunk], 1 KiB
    __shared__ int   csrS[4][64];     // pre-clamped sources, 1 KiB
    int head = blockIdx.x / nodeBlocks;
    int nb = blockIdx.x - head * nodeBlocks;
    int wid = threadIdx.x >> 6;
    int n = nb * 4 + wid;
    if (n >= N) return;
    int lane = threadIdx.x & 63;
    int g = lane >> 4;                // edge group 0..3
    int p = lane & 15;                // channel-lane within group

    int off0 = off[n];
    int degp = off[n + 1] - off0;     // multiple of 4 (padded)
    float aldh = ald[n * 4 + head];
    const char* hB = (const char*)h;
    const unsigned offp = (unsigned)(head * 256 + p * 16);   // bytes within row

    float acc[8] = {};
    float den = 0.f;

    for (int base = 0; base < degp; base += 64) {
        // ---- prepass: one alpha per edge at this head; clamp csr once ----
        float av = 0.f;
        int sc = 0;
        int e = base + lane;
        if (e < degp) {
            int s = csr[off0 + e];
            if (s >= 0) {
                sc = s;
                float l = als[(size_t)(unsigned)s * 4 + head] + aldh;
                l = l > 0.f ? l : 0.2f * l;
                av = __expf(l);
            }
        }
        alpS[wid][lane] = av;
        csrS[wid][lane] = sc;
        // single-wave LDS producer->consumer: DS pipe is in-order per wave

        // ---- quad loop: groups split the (up to) 16 quads of this chunk ----
        int qn = (degp - base) >> 2; if (qn > 16) qn = 16;
        for (int qq = g; qq < qn; qq += 4) {
            int4 cs = *(const int4*)&csrS[wid][qq * 4];
            f32x4 af = *(const f32x4*)&alpS[wid][qq * 4];
            uint4 h0 = *(const uint4*)(hB + (size_t)((((unsigned)cs.x) << 10) + offp));
            uint4 h1 = *(const uint4*)(hB + (size_t)((((unsigned)cs.y) << 10) + offp));
            uint4 h2 = *(const uint4*)(hB + (size_t)((((unsigned)cs.z) << 10) + offp));
            uint4 h3 = *(const uint4*)(hB + (size_t)((((unsigned)cs.w) << 10) + offp));
            den += (af[0] + af[1]) + (af[2] + af[3]);
            unsigned w0[4] = {h0.x, h0.y, h0.z, h0.w};
            unsigned w1[4] = {h1.x, h1.y, h1.z, h1.w};
            unsigned w2[4] = {h2.x, h2.y, h2.z, h2.w};
            unsigned w3[4] = {h3.x, h3.y, h3.z, h3.w};
#pragma unroll
            for (int wv = 0; wv < 4; ++wv) {
                fma_mix_lo(acc[2 * wv],     af[0], w0[wv]);
                fma_mix_hi(acc[2 * wv + 1], af[0], w0[wv]);
            }
#pragma unroll
            for (int wv = 0; wv < 4; ++wv) {
                fma_mix_lo(acc[2 * wv],     af[1], w1[wv]);
                fma_mix_hi(acc[2 * wv + 1], af[1], w1[wv]);
            }
#pragma unroll
            for (int wv = 0; wv < 4; ++wv) {
                fma_mix_lo(acc[2 * wv],     af[2], w2[wv]);
                fma_mix_hi(acc[2 * wv + 1], af[2], w2[wv]);
            }
#pragma unroll
            for (int wv = 0; wv < 4; ++wv) {
                fma_mix_lo(acc[2 * wv],     af[3], w3[wv]);
                fma_mix_hi(acc[2 * wv + 1], af[3], w3[wv]);
            }
        }
    }

    den += __shfl_xor(den, 16);
    den += __shfl_xor(den, 32);
#pragma unroll
    for (int j = 0; j < 8; ++j) {
        acc[j] += __shfl_xor(acc[j], 16);
        acc[j] += __shfl_xor(acc[j], 32);
    }

    if (g == 0) {
        float inv = 1.f / den;
        int cb = head * 128 + p * 8;
        unsigned ww[4];
#pragma unroll
        for (int wv = 0; wv < 4; ++wv) {
            float v0 = acc[2 * wv] * inv + bias[cb + 2 * wv];
            float v1 = acc[2 * wv + 1] * inv + bias[cb + 2 * wv + 1];
            if (DOELU) {
                v0 = elu_fast(v0);
                v1 = elu_fast(v1);
            }
            ww[wv] = (unsigned)f2h_bits(v0) | ((unsigned)f2h_bits(v1) << 16);
        }
        uint4 o; o.x = ww[0]; o.y = ww[1]; o.z = ww[2]; o.w = ww[3];
        *((uint4*)(outp + (size_t)n * 512 + cb)) = o;
    }
}

// ---------------- layer-3 aggr (HC=64, H=1, fp16 h): prepass + LDS csr ----
// Same skeleton as k_aggr4f: one exp per edge in the prepass (the old aggr1b
// recomputed each edge's exp redundantly in all 16 lanes of a group).
__global__ __launch_bounds__(256) void k_aggr1c(
    const unsigned short* __restrict__ h, const float* __restrict__ als,
    const float* __restrict__ aldv, const int* __restrict__ off,
    const int* __restrict__ csr, const float* __restrict__ bias,
    float* __restrict__ outp, int N)
{
    __shared__ float alpS[4][64];
    __shared__ int   csrS[4][64];
    int wid = threadIdx.x >> 6;
    int n = blockIdx.x * 4 + wid;
    if (n >= N) return;
    int lane = threadIdx.x & 63;
    int g = lane >> 4;
    int p = lane & 15;

    int off0 = off[n];
    int degp = off[n + 1] - off0;
    float aldh = aldv[n];
    const char* hB = (const char*)h;
    const unsigned offp = (unsigned)(p * 8);   // bytes; lane owns 4 fp16 (8B)

    float acc[4] = {};
    float den = 0.f;

    for (int base = 0; base < degp; base += 64) {
        float av = 0.f;
        int sc = 0;
        int e = base + lane;
        if (e < degp) {
            int s = csr[off0 + e];
            if (s >= 0) {
                sc = s;
                float l = als[s] + aldh;
                l = l > 0.f ? l : 0.2f * l;
                av = __expf(l);
            }
        }
        alpS[wid][lane] = av;
        csrS[wid][lane] = sc;

        int qn = (degp - base) >> 2; if (qn > 16) qn = 16;
        for (int qq = g; qq < qn; qq += 4) {
            int4 cs = *(const int4*)&csrS[wid][qq * 4];
            f32x4 af = *(const f32x4*)&alpS[wid][qq * 4];
            uint2 h0 = *(const uint2*)(hB + (size_t)((((unsigned)cs.x) << 7) + offp));
            uint2 h1 = *(const uint2*)(hB + (size_t)((((unsigned)cs.y) << 7) + offp));
            uint2 h2 = *(const uint2*)(hB + (size_t)((((unsigned)cs.z) << 7) + offp));
            uint2 h3 = *(const uint2*)(hB + (size_t)((((unsigned)cs.w) << 7) + offp));
            den += (af[0] + af[1]) + (af[2] + af[3]);
            fma_mix_lo(acc[0], af[0], h0.x);
            fma_mix_hi(acc[1], af[0], h0.x);
            fma_mix_lo(acc[2], af[0], h0.y);
            fma_mix_hi(acc[3], af[0], h0.y);
            fma_mix_lo(acc[0], af[1], h1.x);
            fma_mix_hi(acc[1], af[1], h1.x);
            fma_mix_lo(acc[2], af[1], h1.y);
            fma_mix_hi(acc[3], af[1], h1.y);
            fma_mix_lo(acc[0], af[2], h2.x);
            fma_mix_hi(acc[1], af[2], h2.x);
            fma_mix_lo(acc[2], af[2], h2.y);
            fma_mix_hi(acc[3], af[2], h2.y);
            fma_mix_lo(acc[0], af[3], h3.x);
            fma_mix_hi(acc[1], af[3], h3.x);
            fma_mix_lo(acc[2], af[3], h3.y);
            fma_mix_hi(acc[3], af[3], h3.y);
        }
    }

    den += __shfl_xor(den, 16);
    den += __shfl_xor(den, 32);
#pragma unroll
    for (int j = 0; j < 4; ++j) {
        acc[j] += __shfl_xor(acc[j], 16);
        acc[j] += __shfl_xor(acc[j], 32);
    }
    if (g == 0) {
        float inv = 1.f / den;
        f32x4 o;
#pragma unroll
        for (int j = 0; j < 4; ++j)
            o[j] = acc[j] * inv + bias[p * 4 + j];
        *((f32x4*)(outp + (size_t)n * 64 + p * 4)) = o;
    }
}

// --------------------------------------------------------------------------
extern "C" void kernel_launch(void* const* d_in, const int* in_sizes, int n_in,
                              void* d_out, int out_size, void* d_ws, size_t ws_size,
                              hipStream_t stream)
{
    const float* x   = (const float*)d_in[0];
    const int*   ei  = (const int*)d_in[1];
    const float* W1  = (const float*)d_in[2];
    const float* as1 = (const float*)d_in[3];
    const float* ad1 = (const float*)d_in[4];
    const float* b1  = (const float*)d_in[5];
    const float* W2  = (const float*)d_in[6];
    const float* as2 = (const float*)d_in[7];
    const float* ad2 = (const float*)d_in[8];
    const float* b2  = (const float*)d_in[9];
    const float* W3  = (const float*)d_in[10];
    const float* as3 = (const float*)d_in[11];
    const float* ad3 = (const float*)d_in[12];
    const float* b3  = (const float*)d_in[13];

    const int DIN = 256, HC = 512, DOUT = 64;
    int N = in_sizes[0] / DIN;
    int E = in_sizes[1] / 2;
    int Mcap = E + 4 * N;  // capacity for 4-padded CSR

    // workspace carve-up
    char* w = (char*)d_ws;
    auto alloc = [&](size_t bytes) -> char* {
        char* p = w;
        w += (bytes + 255) & ~(size_t)255;
        return p;
    };
    int* deg    = (int*)alloc((size_t)N * 4);
    int* cur    = (int*)alloc((size_t)N * 4);
    int* off    = (int*)alloc((size_t)(N + 1) * 4);
    int* csr    = (int*)alloc((size_t)Mcap * 4);
    unsigned short* W1T = (unsigned short*)alloc((size_t)HC * DIN * 2);
    unsigned short* W2T = (unsigned short*)alloc((size_t)HC * HC * 2);
    unsigned short* W3T = (unsigned short*)alloc((size_t)DOUT * HC * 2);
    unsigned short* xb  = (unsigned short*)alloc((size_t)N * DIN * 2);
    unsigned short* act = (unsigned short*)alloc((size_t)N * HC * 2);
    unsigned short* hb  = (unsigned short*)alloc((size_t)N * HC * 2);
    unsigned short* hb3 = (unsigned short*)alloc((size_t)N * DOUT * 2);  // fp16 h (layer 3)
    float* als   = (float*)alloc((size_t)N * 4 * 4);
    float* ald   = (float*)alloc((size_t)N * 4 * 4);

    // ---- build: memset(deg) -> prep(+csr init+hist) -> scan -> fill ----
    hipMemsetAsync(deg, 0, (size_t)N * 4, stream);
    int prep_total = DIN * HC + HC * HC + HC * DOUT + N * DIN + Mcap + E;
    k_prep<<<(prep_total + 255) / 256, 256, 0, stream>>>(
        W1, W1T, W2, W2T, W3, W3T, x, xb, csr, Mcap, ei, E, deg, DIN, HC, DOUT, N);
    k_scan<<<1, 1024, 0, stream>>>(deg, off, cur, N);
    k_fill<<<(E + N + 255) / 256, 256, 0, stream>>>(ei, E, N, cur, csr);

    int tiles_m = (N + 63) / 64;
    auto gemm_blocks = [&](int tn) { return (tiles_m * tn + 3) / 4; };
    int tm128 = (N + 127) / 128;
    int nwave_blocks = (N + 3) / 4;
    int nodeBlocks = (N + 3) / 4;

    // ---- layer 1 ----
    k_gemm_lds<<<tm128 * (HC / 64), 256, 0, stream>>>(xb, W1T, hb, N, DIN, HC, HC / 64);
    k_al<512, 4><<<nwave_blocks, 256, 0, stream>>>(hb, as1, ad1, als, ald, N);
    k_aggr4f<true><<<4 * nodeBlocks, 256, 0, stream>>>(hb, als, ald, off, csr, b1, act, N, nodeBlocks);

    // ---- layer 2 ----
    k_gemm_lds<<<tm128 * (HC / 64), 256, 0, stream>>>(act, W2T, hb, N, HC, HC, HC / 64);
    k_al<512, 4><<<nwave_blocks, 256, 0, stream>>>(hb, as2, ad2, als, ald, N);
    k_aggr4f<true><<<4 * nodeBlocks, 256, 0, stream>>>(hb, als, ald, off, csr, b2, act, N, nodeBlocks);

    // ---- layer 3 (fp16 h path; Nc=64, al fused into GEMM epilogue) ----
    k_gemm<true, true><<<gemm_blocks(1), 256, 0, stream>>>(
        act, W3T, hb3, N, HC, DOUT, 1, as3, ad3, als, ald);
    k_aggr1c<<<nwave_blocks, 256, 0, stream>>>(hb3, als, ald, off, csr, b3, (float*)d_out, N);
}

// Round 8
// 263.618 us; speedup vs baseline: 1.1440x; 1.0006x over previous
//
#include <hip/hip_runtime.h>
#include <hip/hip_fp16.h>

typedef _Float16 f16x8 __attribute__((ext_vector_type(8)));
typedef float f32x4 __attribute__((ext_vector_type(4)));

__device__ __forceinline__ unsigned short f2h_bits(float f) {
    __half h = __float2half(f);
    return *reinterpret_cast<unsigned short*>(&h);
}
__device__ __forceinline__ float h2f_bits(unsigned short u) {
    __half h = *reinterpret_cast<__half*>(&u);
    return __half2float(h);
}

// acc += a(f32) * f16_lo(hw)  -- one VOP3P v_fma_mix_f32
__device__ __forceinline__ void fma_mix_lo(float& acc, float a, unsigned hw) {
    asm("v_fma_mix_f32 %0, %1, %2, %0 op_sel_hi:[0,1,0]"
        : "+v"(acc) : "v"(a), "v"(hw));
}
// acc += a(f32) * f16_hi(hw)
__device__ __forceinline__ void fma_mix_hi(float& acc, float a, unsigned hw) {
    asm("v_fma_mix_f32 %0, %1, %2, %0 op_sel:[0,1,0] op_sel_hi:[0,1,0]"
        : "+v"(acc) : "v"(a), "v"(hw));
}

// fast ELU: x>0 ? x : e^x-1  (exp never NaN; select discards the inf branch)
__device__ __forceinline__ float elu_fast(float v) {
    float e = __expf(v) - 1.f;
    return v > 0.f ? v : e;
}

// async 16B global->LDS (DMA path, no VGPR round-trip). LDS dest is
// wave-uniform base + lane*16 (HW rule) -- layout below is linear in lane order.
__device__ __forceinline__ void gload_lds16(const void* g, void* l) {
    __builtin_amdgcn_global_load_lds(
        (const __attribute__((address_space(1))) unsigned int*)g,
        (__attribute__((address_space(3))) unsigned int*)l, 16, 0, 0);
}

// ---------------- prep: W transposes (fp16) + was/wad fold, x cvt, csr, deg --
// was[k,h] = sum_c W[k,128h+c]*a_src[h,c] (f32 math, fp16 store): attention
// logits become 8 extra GEMM columns -> k_al dispatches eliminated (R7).
// deg is zeroed by a preceding hipMemsetAsync (stream-ordered).
__global__ void k_prep(const float* __restrict__ W1, unsigned short* __restrict__ W1T,
                       const float* __restrict__ W2, unsigned short* __restrict__ W2T,
                       const float* __restrict__ W3, unsigned short* __restrict__ W3T,
                       const float* __restrict__ x, unsigned short* __restrict__ xb,
                       int* __restrict__ csr, int Mcap,
                       const int* __restrict__ ei, int E, int* __restrict__ deg,
                       const float* __restrict__ as1, const float* __restrict__ ad1,
                       const float* __restrict__ as2, const float* __restrict__ ad2,
                       int DIN, int HC, int DOUT, int N)
{
    int i = blockIdx.x * blockDim.x + threadIdx.x;
    int n1 = DIN * HC;
    int n2 = n1 + HC * HC;
    int n3 = n2 + HC * DOUT;
    int n4 = n3 + N * DIN;
    int n5 = n4 + Mcap;
    int n6 = n5 + E;
    int n7 = n6 + 8 * DIN;               // was1/wad1
    int n8 = n7 + 8 * HC;                // was2/wad2
    int n9 = n8 + 56 * DIN + 56 * HC;    // zero pad rows 520..575
    if (i < n1) {
        int k = i / HC, n = i - k * HC;
        W1T[n * DIN + k] = f2h_bits(W1[i]);
    } else if (i < n2) {
        int j = i - n1;
        int k = j / HC, n = j - k * HC;
        W2T[n * HC + k] = f2h_bits(W2[j]);
    } else if (i < n3) {
        int j = i - n2;
        int k = j / DOUT, n = j - k * DOUT;
        W3T[n * HC + k] = f2h_bits(W3[j]);
    } else if (i < n4) {
        int j = i - n3;
        xb[j] = f2h_bits(x[j]);
    } else if (i < n5) {
        csr[i - n4] = -1;           // pad sentinel
    } else if (i < n6) {
        atomicAdd(&deg[ei[E + (i - n5)]], 1);
    } else if (i < n7) {
        int j = i - n6;
        int h8 = j / DIN, k = j - h8 * DIN;
        int hh = h8 & 3;
        const float* av = (h8 < 4 ? as1 : ad1) + hh * 128;
        const float* wr = W1 + (size_t)k * HC + hh * 128;
        float s = 0.f;
        for (int c = 0; c < 128; ++c) s += wr[c] * av[c];
        W1T[(size_t)(HC + h8) * DIN + k] = f2h_bits(s);
    } else if (i < n8) {
        int j = i - n7;
        int h8 = j / HC, k = j - h8 * HC;
        int hh = h8 & 3;
        const float* av = (h8 < 4 ? as2 : ad2) + hh * 128;
        const float* wr = W2 + (size_t)k * HC + hh * 128;
        float s = 0.f;
        for (int c = 0; c < 128; ++c) s += wr[c] * av[c];
        W2T[(size_t)(HC + h8) * HC + k] = f2h_bits(s);
    } else if (i < n9) {
        int j = i - n8;
        if (j < 56 * DIN) W1T[(size_t)(HC + 8) * DIN + j] = 0;
        else              W2T[(size_t)(HC + 8) * HC + (j - 56 * DIN)] = 0;
    }
}

// scan of (deg+1) rounded up to multiple of 4 (padded segments)
__global__ void k_scan(const int* __restrict__ deg, int* __restrict__ off,
                       int* __restrict__ cur, int N) {
    __shared__ int sums[1024];
    int t = threadIdx.x;
    int chunk = (N + 1023) >> 10;
    int lo = t * chunk;
    int hi = lo + chunk; if (hi > N) hi = N;
    if (lo > N) lo = N;
    int s = 0;
    for (int i = lo; i < hi; ++i) s += (deg[i] + 4) & ~3;
    sums[t] = s;
    __syncthreads();
    for (int dd = 1; dd < 1024; dd <<= 1) {
        int v = (t >= dd) ? sums[t - dd] : 0;
        __syncthreads();
        sums[t] += v;
        __syncthreads();
    }
    int run = sums[t] - s;  // exclusive prefix
    for (int i = lo; i < hi; ++i) { off[i] = run; cur[i] = run; run += (deg[i] + 4) & ~3; }
    if (t == 1023) off[N] = run;
}
__global__ void k_fill(const int* __restrict__ ei, int E, int N,
                       int* cur, int* __restrict__ csr) {
    int i = blockIdx.x * blockDim.x + threadIdx.x;
    if (i < E) {
        int s = ei[i], d = ei[E + i];
        int pos = atomicAdd(&cur[d], 1);
        csr[pos] = s;
    } else if (i < E + N) {
        int nn = i - E;
        int pos = atomicAdd(&cur[nn], 1);
        csr[pos] = nn;
    }
}

// ---------------- GEMM (layer 3 / small-Nc path): register-only 64x64, fp16 --
// DOAL: fused attention-logit epilogue (valid only when tiles_n==1, i.e. the
// wave's 64 cols are ALL output cols; layer 3, H=1). Per row:
// al_s[row] = sum_col acc*a_src -> 4 FMA + shfl_xor reduce over the 16 r-lanes.
template <bool OUTH, bool DOAL>
__global__ __launch_bounds__(256) void k_gemm(
    const unsigned short* __restrict__ A, const unsigned short* __restrict__ BT,
    void* __restrict__ D, int M, int K, int Nc, int tiles_n,
    const float* __restrict__ asrc, const float* __restrict__ adst,
    float* __restrict__ als, float* __restrict__ ald)
{
    int wid = blockIdx.x * (blockDim.x >> 6) + (threadIdx.x >> 6);
    int tiles_m = (M + 63) >> 6;
    if (wid >= tiles_m * tiles_n) return;
    int lane = threadIdx.x & 63;
    int tm = wid / tiles_n, tn = wid - tm * tiles_n;
    int m0 = tm << 6, n0 = tn << 6;
    int r = lane & 15, q = lane >> 4;

    const unsigned short* Arow[4];
    const unsigned short* Brow[4];
#pragma unroll
    for (int i = 0; i < 4; ++i) {
        int row = m0 + 16 * i + r; row = row < M ? row : M - 1;
        Arow[i] = A + (size_t)row * K + q * 8;
        Brow[i] = BT + (size_t)(n0 + 16 * i + r) * K + q * 8;
    }

    f32x4 acc[4][4] = {};
    f16x8 a[4], b[4], a2[4], b2[4];
#pragma unroll
    for (int i = 0; i < 4; ++i) {
        a[i] = *(const f16x8*)(Arow[i]);
        b[i] = *(const f16x8*)(Brow[i]);
    }
    for (int k0 = 0; k0 < K; k0 += 32) {
        int kn = k0 + 32;
        if (kn < K) {
#pragma unroll
            for (int i = 0; i < 4; ++i) {
                a2[i] = *(const f16x8*)(Arow[i] + kn);
                b2[i] = *(const f16x8*)(Brow[i] + kn);
            }
        }
#pragma unroll
        for (int i = 0; i < 4; ++i)
#pragma unroll
            for (int j = 0; j < 4; ++j)
                acc[i][j] = __builtin_amdgcn_mfma_f32_16x16x32_f16(a[i], b[j], acc[i][j], 0, 0, 0);
        if (kn < K) {
#pragma unroll
            for (int i = 0; i < 4; ++i) { a[i] = a2[i]; b[i] = b2[i]; }
        }
    }
#pragma unroll
    for (int i = 0; i < 4; ++i) {
        int rowb = m0 + 16 * i + q * 4;
#pragma unroll
        for (int rr = 0; rr < 4; ++rr) {
            int row = rowb + rr;
            if (row < M) {
#pragma unroll
                for (int j = 0; j < 4; ++j) {
                    int col = n0 + 16 * j + r;
                    if (OUTH)
                        ((unsigned short*)D)[(size_t)row * Nc + col] = f2h_bits(acc[i][j][rr]);
                    else
                        ((float*)D)[(size_t)row * Nc + col] = acc[i][j][rr];
                }
            }
        }
    }
    if (DOAL) {
        float asl[4], adl[4];
#pragma unroll
        for (int j = 0; j < 4; ++j) { asl[j] = asrc[16 * j + r]; adl[j] = adst[16 * j + r]; }
#pragma unroll
        for (int i = 0; i < 4; ++i) {
#pragma unroll
            for (int rr = 0; rr < 4; ++rr) {
                float s = 0.f, d = 0.f;
#pragma unroll
                for (int j = 0; j < 4; ++j) {
                    s += acc[i][j][rr] * asl[j];
                    d += acc[i][j][rr] * adl[j];
                }
#pragma unroll
                for (int dd = 1; dd < 16; dd <<= 1) {
                    s += __shfl_xor(s, dd);
                    d += __shfl_xor(d, dd);
                }
                int row = m0 + 16 * i + q * 4 + rr;
                if (r == 0 && row < M) { als[row] = s; ald[row] = d; }
            }
        }
    }
}

// ---------------- GEMM (layers 1&2): m97-style 128x64 tile, LDS-staged, fp16 --
// 4 waves (2x2), wave tile 64x32, BK=32. Staging via global_load_lds width 16.
// tiles_n = HC/64 + 1: the LAST column-tile multiplies the was/wad extension
// rows of BT (512..519; 520..575 zero), so its accumulators ARE the attention
// logits -- epilogue writes als/ald (f32, exclusive) instead of D. That
// replaces the k_al dispatch per layer (R7). Other tiles unchanged.
__global__ __launch_bounds__(256) void k_gemm_lds(
    const unsigned short* __restrict__ A, const unsigned short* __restrict__ BT,
    unsigned short* __restrict__ D, int M, int K, int Nc, int tiles_n,
    float* __restrict__ als, float* __restrict__ ald)
{
    __shared__ unsigned short As[128 * 32];   // 8 KiB
    __shared__ unsigned short Bs[64 * 32];    // 4 KiB
    int tm = blockIdx.x / tiles_n, tn = blockIdx.x - tm * tiles_n;
    int m0 = tm << 7, n0 = tn << 6;
    int tid = threadIdx.x;
    int w = tid >> 6, lane = tid & 63;
    int wr = w >> 1, wc = w & 1;
    int r = lane & 15, q = lane >> 4;

    // staging: chunk c = 16 tile-rows; lane l -> row c*16 + l/4, bytes (l&3)*16
    int lrow = lane >> 2;
    int lch = (lane & 3) * 8;                  // in fp16 elements
    int ga0 = m0 + w * 16 + lrow;       if (ga0 >= M) ga0 = M - 1;
    int ga1 = m0 + (w + 4) * 16 + lrow; if (ga1 >= M) ga1 = M - 1;
    const unsigned short* pa0 = A + (size_t)ga0 * K + lch;
    const unsigned short* pa1 = A + (size_t)ga1 * K + lch;
    const unsigned short* pb  = BT + (size_t)(n0 + w * 16 + lrow) * K + lch;
    unsigned short* lA0 = As + w * 512;        // wave-uniform LDS chunk bases
    unsigned short* lA1 = As + (w + 4) * 512;
    unsigned short* lB  = Bs + w * 512;

    const unsigned short* arp = As + (wr * 64 + r) * 32 + q * 8;
    const unsigned short* brp = Bs + (wc * 32 + r) * 32 + q * 8;

    f32x4 acc[4][2] = {};
    for (int k0 = 0; k0 < K; k0 += 32) {
        gload_lds16(pa0 + k0, lA0);
        gload_lds16(pa1 + k0, lA1);
        gload_lds16(pb + k0, lB);
        __syncthreads();                        // compiler drains vmcnt(0) here
        f16x8 a[4], b[2];
#pragma unroll
        for (int i = 0; i < 4; ++i) a[i] = *(const f16x8*)(arp + i * 16 * 32);
#pragma unroll
        for (int j = 0; j < 2; ++j) b[j] = *(const f16x8*)(brp + j * 16 * 32);
#pragma unroll
        for (int i = 0; i < 4; ++i)
#pragma unroll
            for (int j = 0; j < 2; ++j)
                acc[i][j] = __builtin_amdgcn_mfma_f32_16x16x32_f16(a[i], b[j], acc[i][j], 0, 0, 0);
        __syncthreads();                        // protect LDS before next stage
    }
    if (tn == tiles_n - 1) {
        // al tile: col r (wc==0, j==0) maps to BT row 512+r: r<4 -> als head r,
        // r in 4..7 -> ald head r-4. Exclusive f32 writes, no atomics.
        if (wc == 0 && r < 8) {
            float* dst = (r < 4) ? als : ald;
            int hh = r & 3;
#pragma unroll
            for (int i = 0; i < 4; ++i)
#pragma unroll
                for (int rr = 0; rr < 4; ++rr) {
                    int row = m0 + wr * 64 + 16 * i + q * 4 + rr;
                    if (row < M) dst[row * 4 + hh] = acc[i][0][rr];
                }
        }
        return;
    }
#pragma unroll
    for (int i = 0; i < 4; ++i) {
        int rowb = m0 + wr * 64 + 16 * i + q * 4;
#pragma unroll
        for (int rr = 0; rr < 4; ++rr) {
            int row = rowb + rr;
            if (row < M) {
#pragma unroll
                for (int j = 0; j < 2; ++j) {
                    int col = n0 + wc * 32 + 16 * j + r;
                    D[(size_t)row * Nc + col] = f2h_bits(acc[i][j][rr]);
                }
            }
        }
    }
}

// ---------------- aggr HC=512 H=4: (node,head) slab, prepass, LDS csr ------
// Wave = (node, head); head-major grid keeps each XCD's h-gather window to a
// 2.56MB head plane (L2-resident; R2: 86% L2 hit). Per 64-edge chunk: PREPASS
// computes alpha(e,head) once per edge (coalesced csr load, 4B als gather,
// wave-uniform ald, 1 exp) and stages BOTH alpha and pre-clamped csr in LDS;
// QUAD loop reads int4 csr + f32x4 alpha via broadcast ds_read. Epilogue ELU
// via exp-1+select (R7: the expm1f expansion was ~200 insts/wave).
template <bool DOELU>
__global__ __launch_bounds__(256) void k_aggr4f(
    const unsigned short* __restrict__ h, const float* __restrict__ als,
    const float* __restrict__ ald,
    const int* __restrict__ off, const int* __restrict__ csr,
    const float* __restrict__ bias,
    unsigned short* __restrict__ outp, int N, int nodeBlocks)
{
    __shared__ float alpS[4][64];     // [wave][edge-in-chunk], 1 KiB
    __shared__ int   csrS[4][64];     // pre-clamped sources, 1 KiB
    int head = blockIdx.x / nodeBlocks;
    int nb = blockIdx.x - head * nodeBlocks;
    int wid = threadIdx.x >> 6;
    int n = nb * 4 + wid;
    if (n >= N) return;
    int lane = threadIdx.x & 63;
    int g = lane >> 4;                // edge group 0..3
    int p = lane & 15;                // channel-lane within group

    int off0 = off[n];
    int degp = off[n + 1] - off0;     // multiple of 4 (padded)
    float aldh = ald[n * 4 + head];
    const char* hB = (const char*)h;
    const unsigned offp = (unsigned)(head * 256 + p * 16);   // bytes within row

    float acc[8] = {};
    float den = 0.f;

    for (int base = 0; base < degp; base += 64) {
        // ---- prepass: one alpha per edge at this head; clamp csr once ----
        float av = 0.f;
        int sc = 0;
        int e = base + lane;
        if (e < degp) {
            int s = csr[off0 + e];
            if (s >= 0) {
                sc = s;
                float l = als[(size_t)(unsigned)s * 4 + head] + aldh;
                l = l > 0.f ? l : 0.2f * l;
                av = __expf(l);
            }
        }
        alpS[wid][lane] = av;
        csrS[wid][lane] = sc;
        // single-wave LDS producer->consumer: DS pipe is in-order per wave

        // ---- quad loop: groups split the (up to) 16 quads of this chunk ----
        int qn = (degp - base) >> 2; if (qn > 16) qn = 16;
        for (int qq = g; qq < qn; qq += 4) {
            int4 cs = *(const int4*)&csrS[wid][qq * 4];
            f32x4 af = *(const f32x4*)&alpS[wid][qq * 4];
            uint4 h0 = *(const uint4*)(hB + (size_t)((((unsigned)cs.x) << 10) + offp));
            uint4 h1 = *(const uint4*)(hB + (size_t)((((unsigned)cs.y) << 10) + offp));
            uint4 h2 = *(const uint4*)(hB + (size_t)((((unsigned)cs.z) << 10) + offp));
            uint4 h3 = *(const uint4*)(hB + (size_t)((((unsigned)cs.w) << 10) + offp));
            den += (af[0] + af[1]) + (af[2] + af[3]);
            unsigned w0[4] = {h0.x, h0.y, h0.z, h0.w};
            unsigned w1[4] = {h1.x, h1.y, h1.z, h1.w};
            unsigned w2[4] = {h2.x, h2.y, h2.z, h2.w};
            unsigned w3[4] = {h3.x, h3.y, h3.z, h3.w};
#pragma unroll
            for (int wv = 0; wv < 4; ++wv) {
                fma_mix_lo(acc[2 * wv],     af[0], w0[wv]);
                fma_mix_hi(acc[2 * wv + 1], af[0], w0[wv]);
            }
#pragma unroll
            for (int wv = 0; wv < 4; ++wv) {
                fma_mix_lo(acc[2 * wv],     af[1], w1[wv]);
                fma_mix_hi(acc[2 * wv + 1], af[1], w1[wv]);
            }
#pragma unroll
            for (int wv = 0; wv < 4; ++wv) {
                fma_mix_lo(acc[2 * wv],     af[2], w2[wv]);
                fma_mix_hi(acc[2 * wv + 1], af[2], w2[wv]);
            }
#pragma unroll
            for (int wv = 0; wv < 4; ++wv) {
                fma_mix_lo(acc[2 * wv],     af[3], w3[wv]);
                fma_mix_hi(acc[2 * wv + 1], af[3], w3[wv]);
            }
        }
    }

    den += __shfl_xor(den, 16);
    den += __shfl_xor(den, 32);
#pragma unroll
    for (int j = 0; j < 8; ++j) {
        acc[j] += __shfl_xor(acc[j], 16);
        acc[j] += __shfl_xor(acc[j], 32);
    }

    if (g == 0) {
        float inv = 1.f / den;
        int cb = head * 128 + p * 8;
        unsigned ww[4];
#pragma unroll
        for (int wv = 0; wv < 4; ++wv) {
            float v0 = acc[2 * wv] * inv + bias[cb + 2 * wv];
            float v1 = acc[2 * wv + 1] * inv + bias[cb + 2 * wv + 1];
            if (DOELU) {
                v0 = elu_fast(v0);
                v1 = elu_fast(v1);
            }
            ww[wv] = (unsigned)f2h_bits(v0) | ((unsigned)f2h_bits(v1) << 16);
        }
        uint4 o; o.x = ww[0]; o.y = ww[1]; o.z = ww[2]; o.w = ww[3];
        *((uint4*)(outp + (size_t)n * 512 + cb)) = o;
    }
}

// ---------------- layer-3 aggr (HC=64, H=1, fp16 h): prepass + LDS csr ----
__global__ __launch_bounds__(256) void k_aggr1c(
    const unsigned short* __restrict__ h, const float* __restrict__ als,
    const float* __restrict__ aldv, const int* __restrict__ off,
    const int* __restrict__ csr, const float* __restrict__ bias,
    float* __restrict__ outp, int N)
{
    __shared__ float alpS[4][64];
    __shared__ int   csrS[4][64];
    int wid = threadIdx.x >> 6;
    int n = blockIdx.x * 4 + wid;
    if (n >= N) return;
    int lane = threadIdx.x & 63;
    int g = lane >> 4;
    int p = lane & 15;

    int off0 = off[n];
    int degp = off[n + 1] - off0;
    float aldh = aldv[n];
    const char* hB = (const char*)h;
    const unsigned offp = (unsigned)(p * 8);   // bytes; lane owns 4 fp16 (8B)

    float acc[4] = {};
    float den = 0.f;

    for (int base = 0; base < degp; base += 64) {
        float av = 0.f;
        int sc = 0;
        int e = base + lane;
        if (e < degp) {
            int s = csr[off0 + e];
            if (s >= 0) {
                sc = s;
                float l = als[s] + aldh;
                l = l > 0.f ? l : 0.2f * l;
                av = __expf(l);
            }
        }
        alpS[wid][lane] = av;
        csrS[wid][lane] = sc;

        int qn = (degp - base) >> 2; if (qn > 16) qn = 16;
        for (int qq = g; qq < qn; qq += 4) {
            int4 cs = *(const int4*)&csrS[wid][qq * 4];
            f32x4 af = *(const f32x4*)&alpS[wid][qq * 4];
            uint2 h0 = *(const uint2*)(hB + (size_t)((((unsigned)cs.x) << 7) + offp));
            uint2 h1 = *(const uint2*)(hB + (size_t)((((unsigned)cs.y) << 7) + offp));
            uint2 h2 = *(const uint2*)(hB + (size_t)((((unsigned)cs.z) << 7) + offp));
            uint2 h3 = *(const uint2*)(hB + (size_t)((((unsigned)cs.w) << 7) + offp));
            den += (af[0] + af[1]) + (af[2] + af[3]);
            fma_mix_lo(acc[0], af[0], h0.x);
            fma_mix_hi(acc[1], af[0], h0.x);
            fma_mix_lo(acc[2], af[0], h0.y);
            fma_mix_hi(acc[3], af[0], h0.y);
            fma_mix_lo(acc[0], af[1], h1.x);
            fma_mix_hi(acc[1], af[1], h1.x);
            fma_mix_lo(acc[2], af[1], h1.y);
            fma_mix_hi(acc[3], af[1], h1.y);
            fma_mix_lo(acc[0], af[2], h2.x);
            fma_mix_hi(acc[1], af[2], h2.x);
            fma_mix_lo(acc[2], af[2], h2.y);
            fma_mix_hi(acc[3], af[2], h2.y);
            fma_mix_lo(acc[0], af[3], h3.x);
            fma_mix_hi(acc[1], af[3], h3.x);
            fma_mix_lo(acc[2], af[3], h3.y);
            fma_mix_hi(acc[3], af[3], h3.y);
        }
    }

    den += __shfl_xor(den, 16);
    den += __shfl_xor(den, 32);
#pragma unroll
    for (int j = 0; j < 4; ++j) {
        acc[j] += __shfl_xor(acc[j], 16);
        acc[j] += __shfl_xor(acc[j], 32);
    }
    if (g == 0) {
        float inv = 1.f / den;
        f32x4 o;
#pragma unroll
        for (int j = 0; j < 4; ++j)
            o[j] = acc[j] * inv + bias[p * 4 + j];
        *((f32x4*)(outp + (size_t)n * 64 + p * 4)) = o;
    }
}

// --------------------------------------------------------------------------
extern "C" void kernel_launch(void* const* d_in, const int* in_sizes, int n_in,
                              void* d_out, int out_size, void* d_ws, size_t ws_size,
                              hipStream_t stream)
{
    const float* x   = (const float*)d_in[0];
    const int*   ei  = (const int*)d_in[1];
    const float* W1  = (const float*)d_in[2];
    const float* as1 = (const float*)d_in[3];
    const float* ad1 = (const float*)d_in[4];
    const float* b1  = (const float*)d_in[5];
    const float* W2  = (const float*)d_in[6];
    const float* as2 = (const float*)d_in[7];
    const float* ad2 = (const float*)d_in[8];
    const float* b2  = (const float*)d_in[9];
    const float* W3  = (const float*)d_in[10];
    const float* as3 = (const float*)d_in[11];
    const float* ad3 = (const float*)d_in[12];
    const float* b3  = (const float*)d_in[13];

    const int DIN = 256, HC = 512, DOUT = 64;
    const int EXT = 64;                 // was/wad + zero-pad extension rows
    int N = in_sizes[0] / DIN;
    int E = in_sizes[1] / 2;
    int Mcap = E + 4 * N;  // capacity for 4-padded CSR

    // workspace carve-up
    char* w = (char*)d_ws;
    auto alloc = [&](size_t bytes) -> char* {
        char* p = w;
        w += (bytes + 255) & ~(size_t)255;
        return p;
    };
    int* deg    = (int*)alloc((size_t)N * 4);
    int* cur    = (int*)alloc((size_t)N * 4);
    int* off    = (int*)alloc((size_t)(N + 1) * 4);
    int* csr    = (int*)alloc((size_t)Mcap * 4);
    unsigned short* W1T = (unsigned short*)alloc((size_t)(HC + EXT) * DIN * 2);
    unsigned short* W2T = (unsigned short*)alloc((size_t)(HC + EXT) * HC * 2);
    unsigned short* W3T = (unsigned short*)alloc((size_t)DOUT * HC * 2);
    unsigned short* xb  = (unsigned short*)alloc((size_t)N * DIN * 2);
    unsigned short* act = (unsigned short*)alloc((size_t)N * HC * 2);
    unsigned short* hb  = (unsigned short*)alloc((size_t)N * HC * 2);
    unsigned short* hb3 = (unsigned short*)alloc((size_t)N * DOUT * 2);  // fp16 h (layer 3)
    float* als   = (float*)alloc((size_t)N * 4 * 4);
    float* ald   = (float*)alloc((size_t)N * 4 * 4);

    // ---- build: memset(deg) -> prep(+csr init+hist+was/wad) -> scan -> fill
    hipMemsetAsync(deg, 0, (size_t)N * 4, stream);
    int prep_total = DIN * HC + HC * HC + HC * DOUT + N * DIN + Mcap + E
                   + 8 * DIN + 8 * HC + 56 * DIN + 56 * HC;
    k_prep<<<(prep_total + 255) / 256, 256, 0, stream>>>(
        W1, W1T, W2, W2T, W3, W3T, x, xb, csr, Mcap, ei, E, deg,
        as1, ad1, as2, ad2, DIN, HC, DOUT, N);
    k_scan<<<1, 1024, 0, stream>>>(deg, off, cur, N);
    k_fill<<<(E + N + 255) / 256, 256, 0, stream>>>(ei, E, N, cur, csr);

    int tiles_m = (N + 63) / 64;
    auto gemm_blocks = [&](int tn) { return (tiles_m * tn + 3) / 4; };
    int tm128 = (N + 127) / 128;
    int tiles_n12 = HC / 64 + 1;        // 8 data tiles + 1 al tile
    int nwave_blocks = (N + 3) / 4;
    int nodeBlocks = (N + 3) / 4;

    // ---- layer 1 ----
    k_gemm_lds<<<tm128 * tiles_n12, 256, 0, stream>>>(xb, W1T, hb, N, DIN, HC, tiles_n12, als, ald);
    k_aggr4f<true><<<4 * nodeBlocks, 256, 0, stream>>>(hb, als, ald, off, csr, b1, act, N, nodeBlocks);

    // ---- layer 2 ----
    k_gemm_lds<<<tm128 * tiles_n12, 256, 0, stream>>>(act, W2T, hb, N, HC, HC, tiles_n12, als, ald);
    k_aggr4f<true><<<4 * nodeBlocks, 256, 0, stream>>>(hb, als, ald, off, csr, b2, act, N, nodeBlocks);

    // ---- layer 3 (fp16 h path; Nc=64, al fused into GEMM epilogue) ----
    k_gemm<true, true><<<gemm_blocks(1), 256, 0, stream>>>(
        act, W3T, hb3, N, HC, DOUT, 1, as3, ad3, als, ald);
    k_aggr1c<<<nwave_blocks, 256, 0, stream>>>(hb3, als, ald, off, csr, b3, (float*)d_out, N);
}